// Round 7
// baseline (1662.086 us; speedup 1.0000x reference)
//
#include <hip/hip_runtime.h>
#include <hip/hip_bf16.h>

typedef unsigned short u16;
typedef unsigned int   u32;
typedef __attribute__((ext_vector_type(8))) short short8;   // 8 x bf16 (4 VGPRs)
typedef __attribute__((ext_vector_type(4))) float f32x4;

#define DEVINL static __device__ __forceinline__

// round-to-nearest-even f32 -> bf16
DEVINL u16 f2bf(float x) {
  u32 u = __float_as_uint(x);
  u32 r = (u + 0x7fffu + ((u >> 16) & 1u)) >> 16;
  return (u16)r;
}

// async global->LDS, 16B per lane. LDS dest = uniform base + lane*16.
#define GLD16(gp, lp) __builtin_amdgcn_global_load_lds(                     \
    (const __attribute__((address_space(1))) u32*)(gp),                     \
    (__attribute__((address_space(3))) u32*)(lp), 16, 0, 0)

// ---------------------------------------------------------------------------
// fp32 -> bf16 bulk convert (n4 = n/4 float4 chunks)
__global__ __launch_bounds__(256) void conv_kernel(const float* __restrict__ s,
                                                   u16* __restrict__ d, int n4) {
  int i = blockIdx.x * 256 + threadIdx.x;
  if (i < n4) {
    float4 v = ((const float4*)s)[i];
    ushort4 o;
    o.x = f2bf(v.x); o.y = f2bf(v.y); o.z = f2bf(v.z); o.w = f2bf(v.w);
    ((ushort4*)d)[i] = o;
  }
}

// cond_e gather + fused bias vectors (bih+bhh)
__global__ __launch_bounds__(256) void prep_small(
    const int* __restrict__ cond, const float* __restrict__ emb_cond,
    const float* __restrict__ bihN, const float* __restrict__ bhhN,
    const float* __restrict__ bihD, const float* __restrict__ bhhD,
    float* __restrict__ ce, float* __restrict__ biasN, float* __restrict__ biasD) {
  int tid = blockIdx.x * 256 + threadIdx.x;
  if (tid < 512) {
    int b = tid >> 3, j = tid & 7;
    ce[tid] = emb_cond[cond[b] * 8 + j];
  }
  int i = tid - 512;
  if (i >= 0 && i < 4096) {
    biasN[i] = bihN[i] + bhhN[i];
    biasD[i] = bihD[i] + bhhD[i];
  }
}

// encoder h0 = [zeros(B,1016), cond_e] -> bf16 into hbuf[0]; c0 = 0
__global__ __launch_bounds__(256) void init_enc(const float* __restrict__ ce,
                                                u16* __restrict__ hb0,
                                                float* __restrict__ c) {
  int tid = blockIdx.x * 256 + threadIdx.x;   // 64*1024
  int b = tid >> 10, col = tid & 1023;
  float v = (col >= 1016) ? ce[b * 8 + (col - 1016)] : 0.f;
  hb0[tid] = f2bf(v);
  c[tid] = 0.f;
}

// embedding row gather -> bf16, X[t*64+b][1024]
__global__ __launch_bounds__(256) void gather_kernel(const float* __restrict__ emb,
                                                     const int* __restrict__ words,
                                                     u16* __restrict__ X, int dec) {
  int r = blockIdx.x;                    // r = t*64 + b
  int t = r >> 6, b = r & 63;
  int tok = dec ? ((t == 0) ? 0 : words[b * 64 + t - 1]) : words[b * 64 + t];
  float4 v = ((const float4*)(emb + (size_t)tok * 1024))[threadIdx.x];
  ushort4 o;
  o.x = f2bf(v.x); o.y = f2bf(v.y); o.z = f2bf(v.z); o.w = f2bf(v.w);
  ((ushort4*)(X + (size_t)r * 1024))[threadIdx.x] = o;
}

// ---------------------------------------------------------------------------
// C = A(MxK) * B(NxK)^T + bias, bf16 in, fp32 out. 128x128 tile, BK=32.
// Grid: x = M/128 (FAST dim), y = N/128. Consecutive orig ids walk m-tiles
// at fixed n -> they share the B n-panel. Bijective XCD swizzle gives each
// XCD a contiguous orig chunk (~31 n-panels x all m): each B panel is HBM-
// fetched by ~1 XCD (~64MB total), A panels (8MB) are L3-resident.
// NT: nontemporal C stores (512MB logits stream must not evict W_out).
template <bool NT>
__global__ __launch_bounds__(256) void gemm_bt_kernel(
    const u16* __restrict__ A, const u16* __restrict__ B,
    float* __restrict__ C, const float* __restrict__ bias, int N, int K) {
  __shared__ u16 lA[128 * 32];
  __shared__ u16 lB[128 * 32];
  const int tid = threadIdx.x;
  const int lane = tid & 63;
  const int wid = tid >> 6;

  const int nm = gridDim.x;                      // # m-tiles
  const int nwg = nm * gridDim.y;
  const int orig = blockIdx.y * nm + blockIdx.x; // m-fast linear id
  const int wgid = (orig & 7) * (nwg >> 3) + (orig >> 3);   // XCD swizzle
  const int tile_m = (wgid % nm) * 128;
  const int tile_n = (wgid / nm) * 128;
  const int wm = wid >> 1, wn = wid & 1;

  const int ldr = lane >> 2;
  const int lko = (lane & 3) * 8;

  f32x4 acc[4][4];
#pragma unroll
  for (int i = 0; i < 4; ++i)
#pragma unroll
    for (int j = 0; j < 4; ++j) acc[i][j] = (f32x4)0.f;

  const size_t aBase = (size_t)tile_m * K;
  const size_t bBase = (size_t)tile_n * K;

  for (int k0 = 0; k0 < K; k0 += 32) {
    __syncthreads();
#pragma unroll
    for (int q = 0; q < 2; ++q) {
      int ch = wid * 2 + q;
      int row = ch * 16 + ldr;
      GLD16(A + aBase + (size_t)row * K + k0 + lko, &lA[ch * 512]);
      GLD16(B + bBase + (size_t)row * K + k0 + lko, &lB[ch * 512]);
    }
    __syncthreads();
    short8 af[4], bf[4];
#pragma unroll
    for (int i = 0; i < 4; ++i)
      af[i] = *(const short8*)&lA[(wm * 64 + i * 16 + (lane & 15)) * 32 + (lane >> 4) * 8];
#pragma unroll
    for (int j = 0; j < 4; ++j)
      bf[j] = *(const short8*)&lB[(wn * 64 + j * 16 + (lane & 15)) * 32 + (lane >> 4) * 8];
#pragma unroll
    for (int i = 0; i < 4; ++i)
#pragma unroll
      for (int j = 0; j < 4; ++j)
        acc[i][j] = __builtin_amdgcn_mfma_f32_16x16x32_bf16(af[i], bf[j], acc[i][j], 0, 0, 0);
  }

#pragma unroll
  for (int i = 0; i < 4; ++i) {
    int row0 = tile_m + wm * 64 + i * 16 + ((lane >> 4) << 2);
#pragma unroll
    for (int j = 0; j < 4; ++j) {
      int col = tile_n + wn * 64 + j * 16 + (lane & 15);
      float bv = bias[col];
#pragma unroll
      for (int e = 0; e < 4; ++e) {
        size_t o = (size_t)(row0 + e) * (size_t)N + col;
        float v = acc[i][j][e] + bv;
        if (NT) __builtin_nontemporal_store(v, &C[o]);
        else    C[o] = v;
      }
    }
  }
}

// ---------------------------------------------------------------------------
// One LSTM step, 256 WGs (64 col-groups x 4 batch-groups) x 256 threads.
// WG (cg,bg): h-cols [cg*16,cg*16+16), batches [bg*16,bg*16+16). Wave = gate.
// A (16x1024 h-block) staged ONCE per WG into XOR-swizzled LDS via GLD16
// (pre-swizzled source, linear dest); B (Whh) bulk-preloaded into 32 short8
// regs before the barrier. c operand prefetched at top (L2 latency hidden
// under staging); Xp streamed with nontemporal loads (read-once data, keep
// L2 for Whh/h). hsd written in [b*64+t] order (contiguous logits GEMM A).
__global__ __launch_bounds__(256) void lstm_step2(
    const u16* __restrict__ hb,    // h_t bf16 [64][1024]
    const u16* __restrict__ Whh,   // bf16 [4096][1024]
    const float* __restrict__ Xp,  // fp32 [4096][4096] (x@Wih^T + bih + bhh)
    float* __restrict__ c,         // fp32 [64][1024], in-place
    u16* __restrict__ hb_n,        // h_{t+1} bf16
    u16* __restrict__ hs_out,      // decoder: hsd base ([b*64+t] order), else null
    float* __restrict__ hT_out,    // encoder t==63: fp32 h_T, else null
    int t) {
  __shared__ __align__(16) char smemA[32768];   // 16 rows x 2048B, XOR-swizzled
  __shared__ float lg[4][16][16];               // [gate][batch][col]
  const int tid = threadIdx.x;
  const int lane = tid & 63;
  const int wid = tid >> 6;        // gate
  const int cg = blockIdx.x >> 2;
  const int bg = blockIdx.x & 3;
  const int hc0 = cg * 16;
  const int b0 = bg * 16;
  const int l15 = lane & 15;
  const int g4 = lane >> 4;
  const int kof = g4 * 8;

  // ---- epilogue indices + operand prefetch (issue now, consumed at the end)
  const int bb = tid >> 4, n = tid & 15;
  const int b = b0 + bb, col = hc0 + n;
  const int ci = b * 1024 + col;
  const float cin = c[ci];
  const size_t xrow = (size_t)(t * 64 + b) * 4096 + col;
  const float xg0 = __builtin_nontemporal_load(&Xp[xrow]);
  const float xg1 = __builtin_nontemporal_load(&Xp[xrow + 1024]);
  const float xg2 = __builtin_nontemporal_load(&Xp[xrow + 2048]);
  const float xg3 = __builtin_nontemporal_load(&Xp[xrow + 3072]);

  // ---- stage A block -> LDS, inverse-swizzled source, linear dest
  const char* hbase = (const char*)(hb + (size_t)b0 * 1024);
#pragma unroll
  for (int q = 0; q < 8; ++q) {
    int o = q * 4096 + wid * 1024 + lane * 16;     // linear LDS byte offset
    int row = o >> 11;                              // 0..15
    int cb = o & 2047;
    const char* src = hbase + row * 2048 + (cb ^ ((row & 7) << 4));
    GLD16(src, smemA + q * 4096 + wid * 1024);
  }

  // ---- bulk-preload B fragments (this wave's gate, 16 cols, full K)
  const u16* Brow = Whh + (size_t)(wid * 1024 + hc0 + l15) * 1024 + kof;
  short8 breg[32];
#pragma unroll
  for (int kk = 0; kk < 32; ++kk)
    breg[kk] = *(const short8*)(Brow + kk * 32);

  __syncthreads();   // drains GLD16 + breg loads; A now in LDS

  // ---- 32 MFMAs, 4 independent chains, A from swizzled LDS
  f32x4 acc[4];
#pragma unroll
  for (int i = 0; i < 4; ++i) acc[i] = (f32x4)0.f;
#pragma unroll
  for (int kk = 0; kk < 32; ++kk) {
    int cb = kk * 64 + g4 * 16;
    const short8 a = *(const short8*)(smemA + l15 * 2048 + (cb ^ ((l15 & 7) << 4)));
    acc[kk & 3] = __builtin_amdgcn_mfma_f32_16x16x32_bf16(a, breg[kk], acc[kk & 3], 0, 0, 0);
  }
  f32x4 asum = acc[0] + acc[1] + acc[2] + acc[3];
  {
    int m = g4 * 4;
#pragma unroll
    for (int e = 0; e < 4; ++e) lg[wid][m + e][l15] = asum[e];
  }
  __syncthreads();

  // ---- cell update: 1 cell per thread
  float gi = lg[0][bb][n] + xg0;
  float gf = lg[1][bb][n] + xg1;
  float gg = lg[2][bb][n] + xg2;
  float go = lg[3][bb][n] + xg3;
  float si = 1.f / (1.f + __expf(-gi));
  float sf = 1.f / (1.f + __expf(-gf));
  float so = 1.f / (1.f + __expf(-go));
  float tg = tanhf(gg);
  float cn = sf * cin + si * tg;
  float hn = so * tanhf(cn);
  c[ci] = cn;
  u16 h16 = f2bf(hn);
  hb_n[ci] = h16;
  if (hs_out) hs_out[((size_t)b * 64 + t) * 1024 + col] = h16;
  if (hT_out) hT_out[ci] = hn;
}

// ---------------------------------------------------------------------------
// mean/logvar/latent + hd0 = [latent|cond_e] @ W_st^T + b_st -> bf16 h0; c=0.
__global__ __launch_bounds__(256) void latent_hd0_kernel(
    const float* hT, const float* Wm, const float* bm,
    const float* Wl, const float* bl, const float* Wst, const float* bst,
    const float* eps, const float* ce, u16* hb0, float* c) {
  __shared__ float red[64][4];
  __shared__ float ml[64];
  __shared__ float lat[40];
  int b = blockIdx.x;
  int tid = threadIdx.x;
  int o = tid >> 2, p = tid & 3;
  const float* w = (o < 32) ? (Wm + (size_t)o * 1024) : (Wl + (size_t)(o - 32) * 1024);
  const float* h = hT + (size_t)b * 1024;
  float s = 0.f;
  for (int k = p * 256; k < p * 256 + 256; ++k) s += h[k] * w[k];
  red[o][p] = s;
  __syncthreads();
  if (tid < 64) {
    float v = red[tid][0] + red[tid][1] + red[tid][2] + red[tid][3];
    v += (tid < 32) ? bm[tid] : bl[tid - 32];
    ml[tid] = v;
  }
  __syncthreads();
  if (tid < 32) lat[tid] = eps[b * 32 + tid] * __expf(0.5f * ml[32 + tid]) + ml[tid];
  if (tid >= 32 && tid < 40) lat[tid] = ce[b * 8 + (tid - 32)];
  __syncthreads();
  for (int hc = tid; hc < 1024; hc += 256) {
    float s2 = bst[hc];
    const float* wr = Wst + (size_t)hc * 40;
#pragma unroll
    for (int j = 0; j < 40; ++j) s2 += lat[j] * wr[j];
    int i = b * 1024 + hc;
    hb0[i] = f2bf(s2);
    c[i] = 0.f;
  }
}

// ---------------------------------------------------------------------------
extern "C" void kernel_launch(void* const* d_in, const int* in_sizes, int n_in,
                              void* d_out, int out_size, void* d_ws, size_t ws_size,
                              hipStream_t stream) {
  const int*   input_word = (const int*)d_in[0];
  const int*   cond       = (const int*)d_in[1];
  const float* emb_N      = (const float*)d_in[2];
  const float* Wih_N      = (const float*)d_in[3];
  const float* Whh_N      = (const float*)d_in[4];
  const float* bih_N      = (const float*)d_in[5];
  const float* bhh_N      = (const float*)d_in[6];
  const float* emb_D      = (const float*)d_in[7];
  const float* Wih_D      = (const float*)d_in[8];
  const float* Whh_D      = (const float*)d_in[9];
  const float* bih_D      = (const float*)d_in[10];
  const float* bhh_D      = (const float*)d_in[11];
  const float* emb_cond   = (const float*)d_in[12];
  const float* W_mean     = (const float*)d_in[13];
  const float* b_mean     = (const float*)d_in[14];
  const float* W_logvar   = (const float*)d_in[15];
  const float* b_logvar   = (const float*)d_in[16];
  const float* W_st       = (const float*)d_in[17];
  const float* b_st       = (const float*)d_in[18];
  const float* W_out      = (const float*)d_in[19];
  const float* b_out      = (const float*)d_in[20];
  const float* eps        = (const float*)d_in[21];
  float* out = (float*)d_out;

  char* ws = (char*)d_ws;
  size_t off = 0;
  auto alloc = [&](size_t b) { size_t p = off; off += (b + 255) & ~(size_t)255; return p; };
  u16*   wihN = (u16*)(ws + alloc(4096ull * 1024 * 2));
  u16*   whhN = (u16*)(ws + alloc(4096ull * 1024 * 2));
  u16*   wihD = (u16*)(ws + alloc(4096ull * 1024 * 2));
  u16*   whhD = (u16*)(ws + alloc(4096ull * 1024 * 2));
  u16*   wout = (u16*)(ws + alloc(32000ull * 1024 * 2));
  u16*   Xe   = (u16*)(ws + alloc(4096ull * 1024 * 2));
  u16*   Xd   = (u16*)(ws + alloc(4096ull * 1024 * 2));
  float* Xp   = (float*)(ws + alloc(4096ull * 4096 * 4));   // enc then dec
  u16*   hsd  = (u16*)(ws + alloc(4096ull * 1024 * 2));     // [b*64+t][1024]
  u16*   hb   = (u16*)(ws + alloc(2ull * 64 * 1024 * 2));   // bf16 h dbuf
  float* hf   = (float*)(ws + alloc(64ull * 1024 * 4));     // fp32 h_T (encoder)
  float* cbuf = (float*)(ws + alloc(64ull * 1024 * 4));     // fp32 cell state
  float* biasN = (float*)(ws + alloc(4096 * 4));
  float* biasD = (float*)(ws + alloc(4096 * 4));
  float* ce    = (float*)(ws + alloc(64 * 8 * 4));
  if (off > ws_size) return;

  conv_kernel<<<4096, 256, 0, stream>>>(Wih_N, wihN, 1048576);
  conv_kernel<<<4096, 256, 0, stream>>>(Whh_N, whhN, 1048576);
  conv_kernel<<<4096, 256, 0, stream>>>(Wih_D, wihD, 1048576);
  conv_kernel<<<4096, 256, 0, stream>>>(Whh_D, whhD, 1048576);
  conv_kernel<<<32000, 256, 0, stream>>>(W_out, wout, 8192000);
  prep_small<<<18, 256, 0, stream>>>(cond, emb_cond, bih_N, bhh_N, bih_D, bhh_D,
                                     ce, biasN, biasD);
  gather_kernel<<<4096, 256, 0, stream>>>(emb_N, input_word, Xe, 0);
  gather_kernel<<<4096, 256, 0, stream>>>(emb_D, input_word, Xd, 1);
  init_enc<<<256, 256, 0, stream>>>(ce, hb, cbuf);

  // encoder precompute + recurrence  (grid: x = m-tiles, y = n-tiles)
  gemm_bt_kernel<false><<<dim3(32, 32), 256, 0, stream>>>(Xe, wihN, Xp, biasN, 4096, 1024);
  for (int t = 0; t < 64; ++t) {
    u16* hcur = hb + (size_t)(t & 1) * 65536;
    u16* hnxt = hb + (size_t)((t + 1) & 1) * 65536;
    lstm_step2<<<256, 256, 0, stream>>>(hcur, whhN, Xp, cbuf, hnxt, nullptr,
                                        (t == 63) ? hf : nullptr, t);
  }
  // latent + decoder h0 (writes hb[0] and re-zeroes cell state)
  latent_hd0_kernel<<<64, 256, 0, stream>>>(hf, W_mean, b_mean, W_logvar, b_logvar,
                                            W_st, b_st, eps, ce, hb, cbuf);
  // decoder precompute + recurrence
  gemm_bt_kernel<false><<<dim3(32, 32), 256, 0, stream>>>(Xd, wihD, Xp, biasD, 4096, 1024);
  for (int t = 0; t < 64; ++t) {
    u16* hcur = hb + (size_t)(t & 1) * 65536;
    u16* hnxt = hb + (size_t)((t + 1) & 1) * 65536;
    lstm_step2<<<256, 256, 0, stream>>>(hcur, whhD, Xp, cbuf, hnxt, hsd, nullptr, t);
  }
  // logits[b][t][:] = hsd[b*64+t] @ W_out^T + b_out (contiguous NT stores)
  gemm_bt_kernel<true><<<dim3(32, 250), 256, 0, stream>>>(hsd, wout, out, b_out, 32000, 1024);
}

// Round 8
// 1586.427 us; speedup vs baseline: 1.0477x; 1.0477x over previous
//
#include <hip/hip_runtime.h>
#include <hip/hip_bf16.h>

typedef unsigned short u16;
typedef unsigned int   u32;
typedef __attribute__((ext_vector_type(8))) short short8;   // 8 x bf16 (4 VGPRs)
typedef __attribute__((ext_vector_type(4))) float f32x4;

#define DEVINL static __device__ __forceinline__

// round-to-nearest-even f32 -> bf16
DEVINL u16 f2bf(float x) {
  u32 u = __float_as_uint(x);
  u32 r = (u + 0x7fffu + ((u >> 16) & 1u)) >> 16;
  return (u16)r;
}

// async global->LDS, 16B per lane. LDS dest = uniform base + lane*16.
#define GLD16(gp, lp) __builtin_amdgcn_global_load_lds(                     \
    (const __attribute__((address_space(1))) u32*)(gp),                     \
    (__attribute__((address_space(3))) u32*)(lp), 16, 0, 0)

// ---------------------------------------------------------------------------
// fp32 -> bf16 bulk convert (n4 = n/4 float4 chunks)
__global__ __launch_bounds__(256) void conv_kernel(const float* __restrict__ s,
                                                   u16* __restrict__ d, int n4) {
  int i = blockIdx.x * 256 + threadIdx.x;
  if (i < n4) {
    float4 v = ((const float4*)s)[i];
    ushort4 o;
    o.x = f2bf(v.x); o.y = f2bf(v.y); o.z = f2bf(v.z); o.w = f2bf(v.w);
    ((ushort4*)d)[i] = o;
  }
}

// cond_e gather + fused bias vectors (bih+bhh)
__global__ __launch_bounds__(256) void prep_small(
    const int* __restrict__ cond, const float* __restrict__ emb_cond,
    const float* __restrict__ bihN, const float* __restrict__ bhhN,
    const float* __restrict__ bihD, const float* __restrict__ bhhD,
    float* __restrict__ ce, float* __restrict__ biasN, float* __restrict__ biasD) {
  int tid = blockIdx.x * 256 + threadIdx.x;
  if (tid < 512) {
    int b = tid >> 3, j = tid & 7;
    ce[tid] = emb_cond[cond[b] * 8 + j];
  }
  int i = tid - 512;
  if (i >= 0 && i < 4096) {
    biasN[i] = bihN[i] + bhhN[i];
    biasD[i] = bihD[i] + bhhD[i];
  }
}

// encoder h0 = [zeros(B,1016), cond_e] -> bf16 into hbuf[0]; c0 = 0
__global__ __launch_bounds__(256) void init_enc(const float* __restrict__ ce,
                                                u16* __restrict__ hb0,
                                                float* __restrict__ c) {
  int tid = blockIdx.x * 256 + threadIdx.x;   // 64*1024
  int b = tid >> 10, col = tid & 1023;
  float v = (col >= 1016) ? ce[b * 8 + (col - 1016)] : 0.f;
  hb0[tid] = f2bf(v);
  c[tid] = 0.f;
}

// embedding row gather -> bf16, X[t*64+b][1024]
__global__ __launch_bounds__(256) void gather_kernel(const float* __restrict__ emb,
                                                     const int* __restrict__ words,
                                                     u16* __restrict__ X, int dec) {
  int r = blockIdx.x;                    // r = t*64 + b
  int t = r >> 6, b = r & 63;
  int tok = dec ? ((t == 0) ? 0 : words[b * 64 + t - 1]) : words[b * 64 + t];
  float4 v = ((const float4*)(emb + (size_t)tok * 1024))[threadIdx.x];
  ushort4 o;
  o.x = f2bf(v.x); o.y = f2bf(v.y); o.z = f2bf(v.z); o.w = f2bf(v.w);
  ((ushort4*)(X + (size_t)r * 1024))[threadIdx.x] = o;
}

// ---------------------------------------------------------------------------
// C = A(MxK) * B(NxK)^T + bias, bf16 in, fp32 out. 128x128 tile, BK=32.
// ROUND-6 mapping (best measured): grid x = N/128 (n-fast), y = M/128.
// Bijective XCD swizzle: each XCD gets a contiguous wgid chunk = few m-rows
// x all n; A-tile stays L2-hot, B streams. NT: nontemporal C stores.
template <bool NT>
__global__ __launch_bounds__(256) void gemm_bt_kernel(
    const u16* __restrict__ A, const u16* __restrict__ B,
    float* __restrict__ C, const float* __restrict__ bias, int N, int K) {
  __shared__ u16 lA[128 * 32];
  __shared__ u16 lB[128 * 32];
  const int tid = threadIdx.x;
  const int lane = tid & 63;
  const int wid = tid >> 6;

  const int nx = gridDim.x;                      // # n-tiles
  const int nwg = nx * gridDim.y;
  const int orig = blockIdx.y * nx + blockIdx.x; // n-fast linear id
  const int wgid = (orig & 7) * (nwg >> 3) + (orig >> 3);   // XCD swizzle
  const int tile_m = (wgid / nx) * 128;
  const int tile_n = (wgid % nx) * 128;
  const int wm = wid >> 1, wn = wid & 1;

  const int ldr = lane >> 2;
  const int lko = (lane & 3) * 8;

  f32x4 acc[4][4];
#pragma unroll
  for (int i = 0; i < 4; ++i)
#pragma unroll
    for (int j = 0; j < 4; ++j) acc[i][j] = (f32x4)0.f;

  const size_t aBase = (size_t)tile_m * K;
  const size_t bBase = (size_t)tile_n * K;

  for (int k0 = 0; k0 < K; k0 += 32) {
    __syncthreads();
#pragma unroll
    for (int q = 0; q < 2; ++q) {
      int ch = wid * 2 + q;
      int row = ch * 16 + ldr;
      GLD16(A + aBase + (size_t)row * K + k0 + lko, &lA[ch * 512]);
      GLD16(B + bBase + (size_t)row * K + k0 + lko, &lB[ch * 512]);
    }
    __syncthreads();
    short8 af[4], bf[4];
#pragma unroll
    for (int i = 0; i < 4; ++i)
      af[i] = *(const short8*)&lA[(wm * 64 + i * 16 + (lane & 15)) * 32 + (lane >> 4) * 8];
#pragma unroll
    for (int j = 0; j < 4; ++j)
      bf[j] = *(const short8*)&lB[(wn * 64 + j * 16 + (lane & 15)) * 32 + (lane >> 4) * 8];
#pragma unroll
    for (int i = 0; i < 4; ++i)
#pragma unroll
      for (int j = 0; j < 4; ++j)
        acc[i][j] = __builtin_amdgcn_mfma_f32_16x16x32_bf16(af[i], bf[j], acc[i][j], 0, 0, 0);
  }

#pragma unroll
  for (int i = 0; i < 4; ++i) {
    int row0 = tile_m + wm * 64 + i * 16 + ((lane >> 4) << 2);
#pragma unroll
    for (int j = 0; j < 4; ++j) {
      int col = tile_n + wn * 64 + j * 16 + (lane & 15);
      float bv = bias[col];
#pragma unroll
      for (int e = 0; e < 4; ++e) {
        size_t o = (size_t)(row0 + e) * (size_t)N + col;
        float v = acc[i][j][e] + bv;
        if (NT) __builtin_nontemporal_store(v, &C[o]);
        else    C[o] = v;
      }
    }
  }
}

// ---------------------------------------------------------------------------
// One LSTM step, 256 WGs x 256 threads. XCD-AFFINITY REMAP: decode
// cg = (i>>5)*8 | (i&7), bg = (i>>3)&3 so all 4 batch-group copies of a
// col-group run on XCD cg%8 -> the 128KB Whh slice is fetched into that
// XCD's L2 once and stays L2-resident across all 64 steps (same block ->
// same XCD each launch). Per-XCD Whh working set 1MB << 4MB L2.
// Wave = gate; A (16x1024 h-block) staged once into XOR-swizzled LDS via
// GLD16; B (Whh) bulk-preloaded into 32 short8 regs; c prefetched; Xp
// streamed nontemporal. hsd written [b*64+t] (contiguous logits GEMM A).
__global__ __launch_bounds__(256) void lstm_step2(
    const u16* __restrict__ hb,    // h_t bf16 [64][1024]
    const u16* __restrict__ Whh,   // bf16 [4096][1024]
    const float* __restrict__ Xp,  // fp32 [4096][4096] (x@Wih^T + bih + bhh)
    float* __restrict__ c,         // fp32 [64][1024], in-place
    u16* __restrict__ hb_n,        // h_{t+1} bf16
    u16* __restrict__ hs_out,      // decoder: hsd base ([b*64+t] order), else null
    float* __restrict__ hT_out,    // encoder t==63: fp32 h_T, else null
    int t) {
  __shared__ __align__(16) char smemA[32768];   // 16 rows x 2048B, XOR-swizzled
  __shared__ float lg[4][16][16];               // [gate][batch][col]
  const int tid = threadIdx.x;
  const int lane = tid & 63;
  const int wid = tid >> 6;        // gate
  const int i = blockIdx.x;
  const int cg = ((i >> 5) << 3) | (i & 7);   // col-group, cg%8 == XCD id
  const int bg = (i >> 3) & 3;                // batch-group
  const int hc0 = cg * 16;
  const int b0 = bg * 16;
  const int l15 = lane & 15;
  const int g4 = lane >> 4;
  const int kof = g4 * 8;

  // ---- epilogue indices + operand prefetch (issue now, consumed at the end)
  const int bb = tid >> 4, n = tid & 15;
  const int b = b0 + bb, col = hc0 + n;
  const int ci = b * 1024 + col;
  const float cin = c[ci];
  const size_t xrow = (size_t)(t * 64 + b) * 4096 + col;
  const float xg0 = __builtin_nontemporal_load(&Xp[xrow]);
  const float xg1 = __builtin_nontemporal_load(&Xp[xrow + 1024]);
  const float xg2 = __builtin_nontemporal_load(&Xp[xrow + 2048]);
  const float xg3 = __builtin_nontemporal_load(&Xp[xrow + 3072]);

  // ---- stage A block -> LDS, inverse-swizzled source, linear dest
  const char* hbase = (const char*)(hb + (size_t)b0 * 1024);
#pragma unroll
  for (int q = 0; q < 8; ++q) {
    int o = q * 4096 + wid * 1024 + lane * 16;     // linear LDS byte offset
    int row = o >> 11;                              // 0..15
    int cb = o & 2047;
    const char* src = hbase + row * 2048 + (cb ^ ((row & 7) << 4));
    GLD16(src, smemA + q * 4096 + wid * 1024);
  }

  // ---- bulk-preload B fragments (this wave's gate, 16 cols, full K)
  const u16* Brow = Whh + (size_t)(wid * 1024 + hc0 + l15) * 1024 + kof;
  short8 breg[32];
#pragma unroll
  for (int kk = 0; kk < 32; ++kk)
    breg[kk] = *(const short8*)(Brow + kk * 32);

  __syncthreads();   // drains GLD16 + breg loads; A now in LDS

  // ---- 32 MFMAs, 4 independent chains, A from swizzled LDS
  f32x4 acc[4];
#pragma unroll
  for (int i2 = 0; i2 < 4; ++i2) acc[i2] = (f32x4)0.f;
#pragma unroll
  for (int kk = 0; kk < 32; ++kk) {
    int cb = kk * 64 + g4 * 16;
    const short8 a = *(const short8*)(smemA + l15 * 2048 + (cb ^ ((l15 & 7) << 4)));
    acc[kk & 3] = __builtin_amdgcn_mfma_f32_16x16x32_bf16(a, breg[kk], acc[kk & 3], 0, 0, 0);
  }
  f32x4 asum = acc[0] + acc[1] + acc[2] + acc[3];
  {
    int m = g4 * 4;
#pragma unroll
    for (int e = 0; e < 4; ++e) lg[wid][m + e][l15] = asum[e];
  }
  __syncthreads();

  // ---- cell update: 1 cell per thread
  float gi = lg[0][bb][n] + xg0;
  float gf = lg[1][bb][n] + xg1;
  float gg = lg[2][bb][n] + xg2;
  float go = lg[3][bb][n] + xg3;
  float si = 1.f / (1.f + __expf(-gi));
  float sf = 1.f / (1.f + __expf(-gf));
  float so = 1.f / (1.f + __expf(-go));
  float tg = tanhf(gg);
  float cn = sf * cin + si * tg;
  float hn = so * tanhf(cn);
  c[ci] = cn;
  u16 h16 = f2bf(hn);
  hb_n[ci] = h16;
  if (hs_out) hs_out[((size_t)b * 64 + t) * 1024 + col] = h16;
  if (hT_out) hT_out[ci] = hn;
}

// ---------------------------------------------------------------------------
// mean/logvar/latent + hd0 = [latent|cond_e] @ W_st^T + b_st -> bf16 h0; c=0.
__global__ __launch_bounds__(256) void latent_hd0_kernel(
    const float* hT, const float* Wm, const float* bm,
    const float* Wl, const float* bl, const float* Wst, const float* bst,
    const float* eps, const float* ce, u16* hb0, float* c) {
  __shared__ float red[64][4];
  __shared__ float ml[64];
  __shared__ float lat[40];
  int b = blockIdx.x;
  int tid = threadIdx.x;
  int o = tid >> 2, p = tid & 3;
  const float* w = (o < 32) ? (Wm + (size_t)o * 1024) : (Wl + (size_t)(o - 32) * 1024);
  const float* h = hT + (size_t)b * 1024;
  float s = 0.f;
  for (int k = p * 256; k < p * 256 + 256; ++k) s += h[k] * w[k];
  red[o][p] = s;
  __syncthreads();
  if (tid < 64) {
    float v = red[tid][0] + red[tid][1] + red[tid][2] + red[tid][3];
    v += (tid < 32) ? bm[tid] : bl[tid - 32];
    ml[tid] = v;
  }
  __syncthreads();
  if (tid < 32) lat[tid] = eps[b * 32 + tid] * __expf(0.5f * ml[32 + tid]) + ml[tid];
  if (tid >= 32 && tid < 40) lat[tid] = ce[b * 8 + (tid - 32)];
  __syncthreads();
  for (int hc = tid; hc < 1024; hc += 256) {
    float s2 = bst[hc];
    const float* wr = Wst + (size_t)hc * 40;
#pragma unroll
    for (int j = 0; j < 40; ++j) s2 += lat[j] * wr[j];
    int i = b * 1024 + hc;
    hb0[i] = f2bf(s2);
    c[i] = 0.f;
  }
}

// ---------------------------------------------------------------------------
extern "C" void kernel_launch(void* const* d_in, const int* in_sizes, int n_in,
                              void* d_out, int out_size, void* d_ws, size_t ws_size,
                              hipStream_t stream) {
  const int*   input_word = (const int*)d_in[0];
  const int*   cond       = (const int*)d_in[1];
  const float* emb_N      = (const float*)d_in[2];
  const float* Wih_N      = (const float*)d_in[3];
  const float* Whh_N      = (const float*)d_in[4];
  const float* bih_N      = (const float*)d_in[5];
  const float* bhh_N      = (const float*)d_in[6];
  const float* emb_D      = (const float*)d_in[7];
  const float* Wih_D      = (const float*)d_in[8];
  const float* Whh_D      = (const float*)d_in[9];
  const float* bih_D      = (const float*)d_in[10];
  const float* bhh_D      = (const float*)d_in[11];
  const float* emb_cond   = (const float*)d_in[12];
  const float* W_mean     = (const float*)d_in[13];
  const float* b_mean     = (const float*)d_in[14];
  const float* W_logvar   = (const float*)d_in[15];
  const float* b_logvar   = (const float*)d_in[16];
  const float* W_st       = (const float*)d_in[17];
  const float* b_st       = (const float*)d_in[18];
  const float* W_out      = (const float*)d_in[19];
  const float* b_out      = (const float*)d_in[20];
  const float* eps        = (const float*)d_in[21];
  float* out = (float*)d_out;

  char* ws = (char*)d_ws;
  size_t off = 0;
  auto alloc = [&](size_t b) { size_t p = off; off += (b + 255) & ~(size_t)255; return p; };
  u16*   wihN = (u16*)(ws + alloc(4096ull * 1024 * 2));
  u16*   whhN = (u16*)(ws + alloc(4096ull * 1024 * 2));
  u16*   wihD = (u16*)(ws + alloc(4096ull * 1024 * 2));
  u16*   whhD = (u16*)(ws + alloc(4096ull * 1024 * 2));
  u16*   wout = (u16*)(ws + alloc(32000ull * 1024 * 2));
  u16*   Xe   = (u16*)(ws + alloc(4096ull * 1024 * 2));
  u16*   Xd   = (u16*)(ws + alloc(4096ull * 1024 * 2));
  float* Xp   = (float*)(ws + alloc(4096ull * 4096 * 4));   // enc then dec
  u16*   hsd  = (u16*)(ws + alloc(4096ull * 1024 * 2));     // [b*64+t][1024]
  u16*   hb   = (u16*)(ws + alloc(2ull * 64 * 1024 * 2));   // bf16 h dbuf
  float* hf   = (float*)(ws + alloc(64ull * 1024 * 4));     // fp32 h_T (encoder)
  float* cbuf = (float*)(ws + alloc(64ull * 1024 * 4));     // fp32 cell state
  float* biasN = (float*)(ws + alloc(4096 * 4));
  float* biasD = (float*)(ws + alloc(4096 * 4));
  float* ce    = (float*)(ws + alloc(64 * 8 * 4));
  if (off > ws_size) return;

  conv_kernel<<<4096, 256, 0, stream>>>(Wih_N, wihN, 1048576);
  conv_kernel<<<4096, 256, 0, stream>>>(Whh_N, whhN, 1048576);
  conv_kernel<<<4096, 256, 0, stream>>>(Wih_D, wihD, 1048576);
  conv_kernel<<<4096, 256, 0, stream>>>(Whh_D, whhD, 1048576);
  conv_kernel<<<32000, 256, 0, stream>>>(W_out, wout, 8192000);
  prep_small<<<18, 256, 0, stream>>>(cond, emb_cond, bih_N, bhh_N, bih_D, bhh_D,
                                     ce, biasN, biasD);
  gather_kernel<<<4096, 256, 0, stream>>>(emb_N, input_word, Xe, 0);
  gather_kernel<<<4096, 256, 0, stream>>>(emb_D, input_word, Xd, 1);
  init_enc<<<256, 256, 0, stream>>>(ce, hb, cbuf);

  // encoder precompute + recurrence  (round-6 GEMM mapping: x = n, y = m)
  gemm_bt_kernel<false><<<dim3(32, 32), 256, 0, stream>>>(Xe, wihN, Xp, biasN, 4096, 1024);
  for (int t = 0; t < 64; ++t) {
    u16* hcur = hb + (size_t)(t & 1) * 65536;
    u16* hnxt = hb + (size_t)((t + 1) & 1) * 65536;
    lstm_step2<<<256, 256, 0, stream>>>(hcur, whhN, Xp, cbuf, hnxt, nullptr,
                                        (t == 63) ? hf : nullptr, t);
  }
  // latent + decoder h0 (writes hb[0] and re-zeroes cell state)
  latent_hd0_kernel<<<64, 256, 0, stream>>>(hf, W_mean, b_mean, W_logvar, b_logvar,
                                            W_st, b_st, eps, ce, hb, cbuf);
  // decoder precompute + recurrence
  gemm_bt_kernel<false><<<dim3(32, 32), 256, 0, stream>>>(Xd, wihD, Xp, biasD, 4096, 1024);
  for (int t = 0; t < 64; ++t) {
    u16* hcur = hb + (size_t)(t & 1) * 65536;
    u16* hnxt = hb + (size_t)((t + 1) & 1) * 65536;
    lstm_step2<<<256, 256, 0, stream>>>(hcur, whhD, Xp, cbuf, hnxt, hsd, nullptr, t);
  }
  // logits[b][t][:] = hsd[b*64+t] @ W_out^T + b_out (contiguous NT stores)
  gemm_bt_kernel<true><<<dim3(250, 32), 256, 0, stream>>>(hsd, wout, out, b_out, 32000, 1024);
}

// Round 9
// 1510.161 us; speedup vs baseline: 1.1006x; 1.0505x over previous
//
#include <hip/hip_runtime.h>
#include <hip/hip_bf16.h>

typedef unsigned short u16;
typedef unsigned int   u32;
typedef __attribute__((ext_vector_type(8))) short short8;   // 8 x bf16 (4 VGPRs)
typedef __attribute__((ext_vector_type(4))) float f32x4;

#define DEVINL static __device__ __forceinline__

// round-to-nearest-even f32 -> bf16
DEVINL u16 f2bf(float x) {
  u32 u = __float_as_uint(x);
  u32 r = (u + 0x7fffu + ((u >> 16) & 1u)) >> 16;
  return (u16)r;
}

// async global->LDS, 16B per lane. LDS dest = uniform base + lane*16.
#define GLD16(gp, lp) __builtin_amdgcn_global_load_lds(                     \
    (const __attribute__((address_space(1))) u32*)(gp),                     \
    (__attribute__((address_space(3))) u32*)(lp), 16, 0, 0)

// ---------------------------------------------------------------------------
// fp32 -> bf16 bulk convert (n4 = n/4 float4 chunks)
__global__ __launch_bounds__(256) void conv_kernel(const float* __restrict__ s,
                                                   u16* __restrict__ d, int n4) {
  int i = blockIdx.x * 256 + threadIdx.x;
  if (i < n4) {
    float4 v = ((const float4*)s)[i];
    ushort4 o;
    o.x = f2bf(v.x); o.y = f2bf(v.y); o.z = f2bf(v.z); o.w = f2bf(v.w);
    ((ushort4*)d)[i] = o;
  }
}

// cond_e gather + fused bias vectors (bih+bhh)
__global__ __launch_bounds__(256) void prep_small(
    const int* __restrict__ cond, const float* __restrict__ emb_cond,
    const float* __restrict__ bihN, const float* __restrict__ bhhN,
    const float* __restrict__ bihD, const float* __restrict__ bhhD,
    float* __restrict__ ce, float* __restrict__ biasN, float* __restrict__ biasD) {
  int tid = blockIdx.x * 256 + threadIdx.x;
  if (tid < 512) {
    int b = tid >> 3, j = tid & 7;
    ce[tid] = emb_cond[cond[b] * 8 + j];
  }
  int i = tid - 512;
  if (i >= 0 && i < 4096) {
    biasN[i] = bihN[i] + bhhN[i];
    biasD[i] = bihD[i] + bhhD[i];
  }
}

// encoder h0 = [zeros(B,1016), cond_e] -> bf16 into hbuf[0]; c0 = 0
__global__ __launch_bounds__(256) void init_enc(const float* __restrict__ ce,
                                                u16* __restrict__ hb0,
                                                float* __restrict__ c) {
  int tid = blockIdx.x * 256 + threadIdx.x;   // 64*1024
  int b = tid >> 10, col = tid & 1023;
  float v = (col >= 1016) ? ce[b * 8 + (col - 1016)] : 0.f;
  hb0[tid] = f2bf(v);
  c[tid] = 0.f;
}

// embedding row gather -> bf16, X[t*64+b][1024]
__global__ __launch_bounds__(256) void gather_kernel(const float* __restrict__ emb,
                                                     const int* __restrict__ words,
                                                     u16* __restrict__ X, int dec) {
  int r = blockIdx.x;                    // r = t*64 + b
  int t = r >> 6, b = r & 63;
  int tok = dec ? ((t == 0) ? 0 : words[b * 64 + t - 1]) : words[b * 64 + t];
  float4 v = ((const float4*)(emb + (size_t)tok * 1024))[threadIdx.x];
  ushort4 o;
  o.x = f2bf(v.x); o.y = f2bf(v.y); o.z = f2bf(v.z); o.w = f2bf(v.w);
  ((ushort4*)(X + (size_t)r * 1024))[threadIdx.x] = o;
}

// ---------------------------------------------------------------------------
// C = A(MxK) * B(NxK)^T + bias, bf16 in, fp32 out. 128x128 tile, BK=32.
// MODE 0 (square Xp GEMMs): n-fast grid + bijective XCD swizzle (round-6).
// MODE 1 (logits, M=4096 N=32000): per-XCD n-partition. Launch 8192 blocks;
//   XCD x (= blockIdx%8, round-robin dispatch) owns n-panels n%8==x, walked
//   mg(8) x kn(32) x mi(4): A window 1MB L2-resident, each B panel HBM-
//   fetched by exactly one XCD and consumed by 4 adjacent blocks. NT stores.
template <int MODE>
__global__ __launch_bounds__(256) void gemm_bt_kernel(
    const u16* __restrict__ A, const u16* __restrict__ B,
    float* __restrict__ C, const float* __restrict__ bias, int N, int K) {
  __shared__ u16 lA[128 * 32];
  __shared__ u16 lB[128 * 32];
  const int tid = threadIdx.x;
  const int lane = tid & 63;
  const int wid = tid >> 6;

  int tile_m, tile_n;
  if (MODE == 0) {
    const int nx = gridDim.x;                      // # n-tiles
    const int nwg = nx * gridDim.y;
    const int orig = blockIdx.y * nx + blockIdx.x; // n-fast linear id
    const int wgid = (orig & 7) * (nwg >> 3) + (orig >> 3);
    tile_m = (wgid / nx) * 128;
    tile_n = (wgid % nx) * 128;
  } else {
    const int i = blockIdx.x;        // 0..8191
    const int x = i & 7;             // XCD id (round-robin dispatch)
    const int k = i >> 3;            // 0..1023 within XCD
    const int mg = k >> 7;           // m-group of 4 (0..7)
    const int r  = k & 127;
    const int kn = r >> 2;           // n-panel slot (0..31)
    const int mi = r & 3;
    const int tn = kn * 8 + x;       // n%8 == x
    if (tn >= 250) return;           // dummy block (250 % 8 != 0 padding)
    tile_m = (mg * 4 + mi) * 128;
    tile_n = tn * 128;
  }
  const int wm = wid >> 1, wn = wid & 1;

  const int ldr = lane >> 2;
  const int lko = (lane & 3) * 8;

  f32x4 acc[4][4];
#pragma unroll
  for (int i = 0; i < 4; ++i)
#pragma unroll
    for (int j = 0; j < 4; ++j) acc[i][j] = (f32x4)0.f;

  const size_t aBase = (size_t)tile_m * K;
  const size_t bBase = (size_t)tile_n * K;

  for (int k0 = 0; k0 < K; k0 += 32) {
    __syncthreads();
#pragma unroll
    for (int q = 0; q < 2; ++q) {
      int ch = wid * 2 + q;
      int row = ch * 16 + ldr;
      GLD16(A + aBase + (size_t)row * K + k0 + lko, &lA[ch * 512]);
      GLD16(B + bBase + (size_t)row * K + k0 + lko, &lB[ch * 512]);
    }
    __syncthreads();
    short8 af[4], bf[4];
#pragma unroll
    for (int i = 0; i < 4; ++i)
      af[i] = *(const short8*)&lA[(wm * 64 + i * 16 + (lane & 15)) * 32 + (lane >> 4) * 8];
#pragma unroll
    for (int j = 0; j < 4; ++j)
      bf[j] = *(const short8*)&lB[(wn * 64 + j * 16 + (lane & 15)) * 32 + (lane >> 4) * 8];
#pragma unroll
    for (int i = 0; i < 4; ++i)
#pragma unroll
      for (int j = 0; j < 4; ++j)
        acc[i][j] = __builtin_amdgcn_mfma_f32_16x16x32_bf16(af[i], bf[j], acc[i][j], 0, 0, 0);
  }

#pragma unroll
  for (int i = 0; i < 4; ++i) {
    int row0 = tile_m + wm * 64 + i * 16 + ((lane >> 4) << 2);
#pragma unroll
    for (int j = 0; j < 4; ++j) {
      int col = tile_n + wn * 64 + j * 16 + (lane & 15);
      float bv = bias[col];
#pragma unroll
      for (int e = 0; e < 4; ++e) {
        size_t o = (size_t)(row0 + e) * (size_t)N + col;
        float v = acc[i][j][e] + bv;
        if (MODE == 1) __builtin_nontemporal_store(v, &C[o]);
        else           C[o] = v;
      }
    }
  }
}

// ---------------------------------------------------------------------------
// One LSTM step, 256 WGs x 512 threads (8 waves = 2 waves/SIMD for latency
// overlap). WG (cg,bg): h-cols [cg*16,+16), batches [bg*16,+16); XCD-affine
// decode keeps each Whh slice on one XCD's L2. Wave w: gate = w>>1, K-half
// = w&1 (512 k's, 16 MFMAs, breg 16 x short8). A staged once into XOR-
// swizzled LDS via GLD16 (pre-swizzled source, linear dest). Partial gates
// summed via 8-slot LDS exchange. hsd written [b*64+t] order.
__global__ __launch_bounds__(512) void lstm_step3(
    const u16* __restrict__ hb,    // h_t bf16 [64][1024]
    const u16* __restrict__ Whh,   // bf16 [4096][1024]
    const float* __restrict__ Xp,  // fp32 [4096][4096]
    float* __restrict__ c,         // fp32 [64][1024], in-place
    u16* __restrict__ hb_n,        // h_{t+1} bf16
    u16* __restrict__ hs_out,      // decoder: hsd base ([b*64+t]), else null
    float* __restrict__ hT_out,    // encoder t==63: fp32 h_T, else null
    int t) {
  __shared__ __align__(16) char smemA[32768];   // 16 rows x 2048B, swizzled
  __shared__ float lg[8][16][16];               // [wave][batch][col]
  const int tid = threadIdx.x;      // 0..511
  const int lane = tid & 63;
  const int w = tid >> 6;           // wave 0..7
  const int gate = w >> 1;
  const int kh = w & 1;             // K-half
  const int i = blockIdx.x;
  const int cg = ((i >> 5) << 3) | (i & 7);   // col-group (cg%8 = XCD)
  const int bg = (i >> 3) & 3;
  const int hc0 = cg * 16;
  const int b0 = bg * 16;
  const int l15 = lane & 15;
  const int g4 = lane >> 4;

  // ---- epilogue operand prefetch (update threads only)
  const int bb = tid >> 4, n = tid & 15;      // valid for tid<256
  const int b = b0 + bb, col = hc0 + n;
  const int ci = b * 1024 + col;
  float cin = 0.f, xg0 = 0.f, xg1 = 0.f, xg2 = 0.f, xg3 = 0.f;
  if (tid < 256) {
    cin = c[ci];
    size_t xrow = (size_t)(t * 64 + b) * 4096 + col;
    xg0 = __builtin_nontemporal_load(&Xp[xrow]);
    xg1 = __builtin_nontemporal_load(&Xp[xrow + 1024]);
    xg2 = __builtin_nontemporal_load(&Xp[xrow + 2048]);
    xg3 = __builtin_nontemporal_load(&Xp[xrow + 3072]);
  }

  // ---- stage A (16x1024 h-block) -> LDS, inverse-swizzled source
  const char* hbase = (const char*)(hb + (size_t)b0 * 1024);
#pragma unroll
  for (int q = 0; q < 4; ++q) {
    int o = q * 8192 + tid * 16;    // linear LDS byte offset
    int row = o >> 11;              // 0..15
    int cb = o & 2047;
    const char* src = hbase + row * 2048 + (cb ^ ((row & 7) << 4));
    GLD16(src, smemA + q * 8192 + w * 1024);
  }

  // ---- bulk-preload B fragments (gate, 16 cols, this wave's K-half)
  const u16* Brow = Whh + (size_t)(gate * 1024 + hc0 + l15) * 1024
                        + kh * 512 + g4 * 8;
  short8 breg[16];
#pragma unroll
  for (int kk = 0; kk < 16; ++kk)
    breg[kk] = *(const short8*)(Brow + kk * 32);

  __syncthreads();   // drains GLD16 + breg loads

  // ---- 16 MFMAs, 4 chains, A from swizzled LDS
  f32x4 acc[4];
#pragma unroll
  for (int j = 0; j < 4; ++j) acc[j] = (f32x4)0.f;
#pragma unroll
  for (int kk = 0; kk < 16; ++kk) {
    int ctrue = (kh * 16 + kk) * 64 + g4 * 16;
    const short8 a = *(const short8*)(smemA + l15 * 2048 + (ctrue ^ ((l15 & 7) << 4)));
    acc[kk & 3] = __builtin_amdgcn_mfma_f32_16x16x32_bf16(a, breg[kk], acc[kk & 3], 0, 0, 0);
  }
  f32x4 asum = acc[0] + acc[1] + acc[2] + acc[3];
  {
    int m = g4 * 4;
#pragma unroll
    for (int e = 0; e < 4; ++e) lg[w][m + e][l15] = asum[e];
  }
  __syncthreads();

  // ---- cell update: 1 cell per thread (tid<256)
  if (tid < 256) {
    float gi = lg[0][bb][n] + lg[1][bb][n] + xg0;
    float gf = lg[2][bb][n] + lg[3][bb][n] + xg1;
    float gg = lg[4][bb][n] + lg[5][bb][n] + xg2;
    float go = lg[6][bb][n] + lg[7][bb][n] + xg3;
    float si = 1.f / (1.f + __expf(-gi));
    float sf = 1.f / (1.f + __expf(-gf));
    float so = 1.f / (1.f + __expf(-go));
    float tg = tanhf(gg);
    float cn = sf * cin + si * tg;
    float hn = so * tanhf(cn);
    c[ci] = cn;
    u16 h16 = f2bf(hn);
    hb_n[ci] = h16;
    if (hs_out) hs_out[((size_t)b * 64 + t) * 1024 + col] = h16;
    if (hT_out) hT_out[ci] = hn;
  }
}

// ---------------------------------------------------------------------------
// mean/logvar/latent + hd0 = [latent|cond_e] @ W_st^T + b_st -> bf16 h0; c=0.
__global__ __launch_bounds__(256) void latent_hd0_kernel(
    const float* hT, const float* Wm, const float* bm,
    const float* Wl, const float* bl, const float* Wst, const float* bst,
    const float* eps, const float* ce, u16* hb0, float* c) {
  __shared__ float red[64][4];
  __shared__ float ml[64];
  __shared__ float lat[40];
  int b = blockIdx.x;
  int tid = threadIdx.x;
  int o = tid >> 2, p = tid & 3;
  const float* w = (o < 32) ? (Wm + (size_t)o * 1024) : (Wl + (size_t)(o - 32) * 1024);
  const float* h = hT + (size_t)b * 1024;
  float s = 0.f;
  for (int k = p * 256; k < p * 256 + 256; ++k) s += h[k] * w[k];
  red[o][p] = s;
  __syncthreads();
  if (tid < 64) {
    float v = red[tid][0] + red[tid][1] + red[tid][2] + red[tid][3];
    v += (tid < 32) ? bm[tid] : bl[tid - 32];
    ml[tid] = v;
  }
  __syncthreads();
  if (tid < 32) lat[tid] = eps[b * 32 + tid] * __expf(0.5f * ml[32 + tid]) + ml[tid];
  if (tid >= 32 && tid < 40) lat[tid] = ce[b * 8 + (tid - 32)];
  __syncthreads();
  for (int hc = tid; hc < 1024; hc += 256) {
    float s2 = bst[hc];
    const float* wr = Wst + (size_t)hc * 40;
#pragma unroll
    for (int j = 0; j < 40; ++j) s2 += lat[j] * wr[j];
    int i = b * 1024 + hc;
    hb0[i] = f2bf(s2);
    c[i] = 0.f;
  }
}

// ---------------------------------------------------------------------------
extern "C" void kernel_launch(void* const* d_in, const int* in_sizes, int n_in,
                              void* d_out, int out_size, void* d_ws, size_t ws_size,
                              hipStream_t stream) {
  const int*   input_word = (const int*)d_in[0];
  const int*   cond       = (const int*)d_in[1];
  const float* emb_N      = (const float*)d_in[2];
  const float* Wih_N      = (const float*)d_in[3];
  const float* Whh_N      = (const float*)d_in[4];
  const float* bih_N      = (const float*)d_in[5];
  const float* bhh_N      = (const float*)d_in[6];
  const float* emb_D      = (const float*)d_in[7];
  const float* Wih_D      = (const float*)d_in[8];
  const float* Whh_D      = (const float*)d_in[9];
  const float* bih_D      = (const float*)d_in[10];
  const float* bhh_D      = (const float*)d_in[11];
  const float* emb_cond   = (const float*)d_in[12];
  const float* W_mean     = (const float*)d_in[13];
  const float* b_mean     = (const float*)d_in[14];
  const float* W_logvar   = (const float*)d_in[15];
  const float* b_logvar   = (const float*)d_in[16];
  const float* W_st       = (const float*)d_in[17];
  const float* b_st       = (const float*)d_in[18];
  const float* W_out      = (const float*)d_in[19];
  const float* b_out      = (const float*)d_in[20];
  const float* eps        = (const float*)d_in[21];
  float* out = (float*)d_out;

  char* ws = (char*)d_ws;
  size_t off = 0;
  auto alloc = [&](size_t b) { size_t p = off; off += (b + 255) & ~(size_t)255; return p; };
  u16*   wihN = (u16*)(ws + alloc(4096ull * 1024 * 2));
  u16*   whhN = (u16*)(ws + alloc(4096ull * 1024 * 2));
  u16*   wihD = (u16*)(ws + alloc(4096ull * 1024 * 2));
  u16*   whhD = (u16*)(ws + alloc(4096ull * 1024 * 2));
  u16*   wout = (u16*)(ws + alloc(32000ull * 1024 * 2));
  u16*   Xe   = (u16*)(ws + alloc(4096ull * 1024 * 2));
  u16*   Xd   = (u16*)(ws + alloc(4096ull * 1024 * 2));
  float* Xp   = (float*)(ws + alloc(4096ull * 4096 * 4));   // enc then dec
  u16*   hsd  = (u16*)(ws + alloc(4096ull * 1024 * 2));     // [b*64+t][1024]
  u16*   hb   = (u16*)(ws + alloc(2ull * 64 * 1024 * 2));   // bf16 h dbuf
  float* hf   = (float*)(ws + alloc(64ull * 1024 * 4));     // fp32 h_T (encoder)
  float* cbuf = (float*)(ws + alloc(64ull * 1024 * 4));     // fp32 cell state
  float* biasN = (float*)(ws + alloc(4096 * 4));
  float* biasD = (float*)(ws + alloc(4096 * 4));
  float* ce    = (float*)(ws + alloc(64 * 8 * 4));
  if (off > ws_size) return;

  conv_kernel<<<4096, 256, 0, stream>>>(Wih_N, wihN, 1048576);
  conv_kernel<<<4096, 256, 0, stream>>>(Whh_N, whhN, 1048576);
  conv_kernel<<<4096, 256, 0, stream>>>(Wih_D, wihD, 1048576);
  conv_kernel<<<4096, 256, 0, stream>>>(Whh_D, whhD, 1048576);
  conv_kernel<<<32000, 256, 0, stream>>>(W_out, wout, 8192000);
  prep_small<<<18, 256, 0, stream>>>(cond, emb_cond, bih_N, bhh_N, bih_D, bhh_D,
                                     ce, biasN, biasD);
  gather_kernel<<<4096, 256, 0, stream>>>(emb_N, input_word, Xe, 0);
  gather_kernel<<<4096, 256, 0, stream>>>(emb_D, input_word, Xd, 1);
  init_enc<<<256, 256, 0, stream>>>(ce, hb, cbuf);

  // encoder precompute + recurrence
  gemm_bt_kernel<0><<<dim3(32, 32), 256, 0, stream>>>(Xe, wihN, Xp, biasN, 4096, 1024);
  for (int t = 0; t < 64; ++t) {
    u16* hcur = hb + (size_t)(t & 1) * 65536;
    u16* hnxt = hb + (size_t)((t + 1) & 1) * 65536;
    lstm_step3<<<256, 512, 0, stream>>>(hcur, whhN, Xp, cbuf, hnxt, nullptr,
                                        (t == 63) ? hf : nullptr, t);
  }
  // latent + decoder h0 (writes hb[0] and re-zeroes cell state)
  latent_hd0_kernel<<<64, 256, 0, stream>>>(hf, W_mean, b_mean, W_logvar, b_logvar,
                                            W_st, b_st, eps, ce, hb, cbuf);
  // decoder precompute + recurrence
  gemm_bt_kernel<0><<<dim3(32, 32), 256, 0, stream>>>(Xd, wihD, Xp, biasD, 4096, 1024);
  for (int t = 0; t < 64; ++t) {
    u16* hcur = hb + (size_t)(t & 1) * 65536;
    u16* hnxt = hb + (size_t)((t + 1) & 1) * 65536;
    lstm_step3<<<256, 512, 0, stream>>>(hcur, whhD, Xp, cbuf, hnxt, hsd, nullptr, t);
  }
  // logits[b][t][:] = hsd[b*64+t] @ W_out^T + b_out (XCD n-partition, NT)
  gemm_bt_kernel<1><<<8192, 256, 0, stream>>>(hsd, wout, out, b_out, 32000, 1024);
}

// Round 10
// 1478.680 us; speedup vs baseline: 1.1240x; 1.0213x over previous
//
#include <hip/hip_runtime.h>
#include <hip/hip_bf16.h>

typedef unsigned short u16;
typedef unsigned int   u32;
typedef __attribute__((ext_vector_type(8))) short short8;   // 8 x bf16 (4 VGPRs)
typedef __attribute__((ext_vector_type(4))) float f32x4;

#define DEVINL static __device__ __forceinline__

// round-to-nearest-even f32 -> bf16
DEVINL u16 f2bf(float x) {
  u32 u = __float_as_uint(x);
  u32 r = (u + 0x7fffu + ((u >> 16) & 1u)) >> 16;
  return (u16)r;
}

// async global->LDS, 16B per lane. LDS dest = uniform base + lane*16.
#define GLD16(gp, lp) __builtin_amdgcn_global_load_lds(                     \
    (const __attribute__((address_space(1))) u32*)(gp),                     \
    (__attribute__((address_space(3))) u32*)(lp), 16, 0, 0)

// ---------------------------------------------------------------------------
// fp32 -> bf16 bulk convert (n4 = n/4 float4 chunks)
__global__ __launch_bounds__(256) void conv_kernel(const float* __restrict__ s,
                                                   u16* __restrict__ d, int n4) {
  int i = blockIdx.x * 256 + threadIdx.x;
  if (i < n4) {
    float4 v = ((const float4*)s)[i];
    ushort4 o;
    o.x = f2bf(v.x); o.y = f2bf(v.y); o.z = f2bf(v.z); o.w = f2bf(v.w);
    ((ushort4*)d)[i] = o;
  }
}

// cond_e gather + fused bias vectors (bih+bhh)
__global__ __launch_bounds__(256) void prep_small(
    const int* __restrict__ cond, const float* __restrict__ emb_cond,
    const float* __restrict__ bihN, const float* __restrict__ bhhN,
    const float* __restrict__ bihD, const float* __restrict__ bhhD,
    float* __restrict__ ce, float* __restrict__ biasN, float* __restrict__ biasD) {
  int tid = blockIdx.x * 256 + threadIdx.x;
  if (tid < 512) {
    int b = tid >> 3, j = tid & 7;
    ce[tid] = emb_cond[cond[b] * 8 + j];
  }
  int i = tid - 512;
  if (i >= 0 && i < 4096) {
    biasN[i] = bihN[i] + bhhN[i];
    biasD[i] = bihD[i] + bhhD[i];
  }
}

// encoder h0 = [zeros(B,1016), cond_e] -> bf16 into hbuf[0]; c0 = 0
__global__ __launch_bounds__(256) void init_enc(const float* __restrict__ ce,
                                                u16* __restrict__ hb0,
                                                float* __restrict__ c) {
  int tid = blockIdx.x * 256 + threadIdx.x;   // 64*1024
  int b = tid >> 10, col = tid & 1023;
  float v = (col >= 1016) ? ce[b * 8 + (col - 1016)] : 0.f;
  hb0[tid] = f2bf(v);
  c[tid] = 0.f;
}

// embedding row gather -> bf16, X[t*64+b][1024]
__global__ __launch_bounds__(256) void gather_kernel(const float* __restrict__ emb,
                                                     const int* __restrict__ words,
                                                     u16* __restrict__ X, int dec) {
  int r = blockIdx.x;                    // r = t*64 + b
  int t = r >> 6, b = r & 63;
  int tok = dec ? ((t == 0) ? 0 : words[b * 64 + t - 1]) : words[b * 64 + t];
  float4 v = ((const float4*)(emb + (size_t)tok * 1024))[threadIdx.x];
  ushort4 o;
  o.x = f2bf(v.x); o.y = f2bf(v.y); o.z = f2bf(v.z); o.w = f2bf(v.w);
  ((ushort4*)(X + (size_t)r * 1024))[threadIdx.x] = o;
}

// ---------------------------------------------------------------------------
// C = A(MxK) * B(NxK)^T + bias, bf16 in, fp32 out. 256x128 tile, BK=32,
// 512 threads = 8 waves (4m x 2n), per-wave 64x64 output (proven fragment
// code from the 128^2 kernel). 1-D grid, exact (no dummies), XCD swizzle:
// XCD x owns an m-tile pair x all n (n-fast): A panels ~1MB L2-hot,
// B streamed once (L3-buffered for other XCDs). NT: nontemporal C stores.
template <bool NT>
__global__ __launch_bounds__(512) void gemm_bt_kernel(
    const u16* __restrict__ A, const u16* __restrict__ B,
    float* __restrict__ C, const float* __restrict__ bias, int N, int K) {
  __shared__ u16 lA[256 * 32];   // 16KB
  __shared__ u16 lB[128 * 32];   // 8KB
  const int tid = threadIdx.x;
  const int lane = tid & 63;
  const int wid = tid >> 6;      // 0..7

  const int nn = N >> 7;                          // # n-tiles (128-wide)
  const int nwg = gridDim.x;
  const int orig = blockIdx.x;
  const int wgid = (orig & 7) * (nwg >> 3) + (orig >> 3);   // XCD swizzle
  const int tile_m = (wgid / nn) * 256;
  const int tile_n = (wgid % nn) * 128;
  const int wm = wid >> 1, wn = wid & 1;          // 4 x 2 waves

  const int ldr = lane >> 2;
  const int lko = (lane & 3) * 8;
  const int l15 = lane & 15;
  const int g4 = lane >> 4;

  f32x4 acc[4][4];
#pragma unroll
  for (int i = 0; i < 4; ++i)
#pragma unroll
    for (int j = 0; j < 4; ++j) acc[i][j] = (f32x4)0.f;

  const size_t aBase = (size_t)tile_m * K;
  const size_t bBase = (size_t)tile_n * K;

  for (int k0 = 0; k0 < K; k0 += 32) {
    __syncthreads();
    // A: 16 chunks of 16 rows (2 per wave); B: 8 chunks (1 per wave)
#pragma unroll
    for (int q = 0; q < 2; ++q) {
      int ch = wid * 2 + q;
      int row = ch * 16 + ldr;
      GLD16(A + aBase + (size_t)row * K + k0 + lko, &lA[ch * 512]);
    }
    {
      int row = wid * 16 + ldr;
      GLD16(B + bBase + (size_t)row * K + k0 + lko, &lB[wid * 512]);
    }
    __syncthreads();
    short8 af[4], bf[4];
#pragma unroll
    for (int i = 0; i < 4; ++i)
      af[i] = *(const short8*)&lA[(wm * 64 + i * 16 + l15) * 32 + g4 * 8];
#pragma unroll
    for (int j = 0; j < 4; ++j)
      bf[j] = *(const short8*)&lB[(wn * 64 + j * 16 + l15) * 32 + g4 * 8];
#pragma unroll
    for (int i = 0; i < 4; ++i)
#pragma unroll
      for (int j = 0; j < 4; ++j)
        acc[i][j] = __builtin_amdgcn_mfma_f32_16x16x32_bf16(af[i], bf[j], acc[i][j], 0, 0, 0);
  }

#pragma unroll
  for (int i = 0; i < 4; ++i) {
    int row0 = tile_m + wm * 64 + i * 16 + (g4 << 2);
#pragma unroll
    for (int j = 0; j < 4; ++j) {
      int col = tile_n + wn * 64 + j * 16 + l15;
      float bv = bias[col];
#pragma unroll
      for (int e = 0; e < 4; ++e) {
        size_t o = (size_t)(row0 + e) * (size_t)N + col;
        float v = acc[i][j][e] + bv;
        if (NT) __builtin_nontemporal_store(v, &C[o]);
        else    C[o] = v;
      }
    }
  }
}

// ---------------------------------------------------------------------------
// One LSTM step, 256 WGs x 512 threads (8 waves). WG (cg,bg): h-cols
// [cg*16,+16), batches [bg*16,+16); XCD-affine decode. Wave w: gate = w>>1,
// K-half = w&1 (16 MFMAs from 16 breg short8). A staged once into XOR-
// swizzled LDS via GLD16 (pre-swizzled source, linear dest). Partials
// summed via 8-slot LDS exchange. hsd written [b*64+t] order.
__global__ __launch_bounds__(512) void lstm_step3(
    const u16* __restrict__ hb,    // h_t bf16 [64][1024]
    const u16* __restrict__ Whh,   // bf16 [4096][1024]
    const float* __restrict__ Xp,  // fp32 [4096][4096]
    float* __restrict__ c,         // fp32 [64][1024], in-place
    u16* __restrict__ hb_n,        // h_{t+1} bf16
    u16* __restrict__ hs_out,      // decoder: hsd base ([b*64+t]), else null
    float* __restrict__ hT_out,    // encoder t==63: fp32 h_T, else null
    int t) {
  __shared__ __align__(16) char smemA[32768];   // 16 rows x 2048B, swizzled
  __shared__ float lg[8][16][16];               // [wave][batch][col]
  const int tid = threadIdx.x;      // 0..511
  const int lane = tid & 63;
  const int w = tid >> 6;           // wave 0..7
  const int gate = w >> 1;
  const int kh = w & 1;             // K-half
  const int i = blockIdx.x;
  const int cg = ((i >> 5) << 3) | (i & 7);   // col-group (cg%8 = XCD)
  const int bg = (i >> 3) & 3;
  const int hc0 = cg * 16;
  const int b0 = bg * 16;
  const int l15 = lane & 15;
  const int g4 = lane >> 4;

  // ---- epilogue operand prefetch (update threads only)
  const int bb = tid >> 4, n = tid & 15;      // valid for tid<256
  const int b = b0 + bb, col = hc0 + n;
  const int ci = b * 1024 + col;
  float cin = 0.f, xg0 = 0.f, xg1 = 0.f, xg2 = 0.f, xg3 = 0.f;
  if (tid < 256) {
    cin = c[ci];
    size_t xrow = (size_t)(t * 64 + b) * 4096 + col;
    xg0 = __builtin_nontemporal_load(&Xp[xrow]);
    xg1 = __builtin_nontemporal_load(&Xp[xrow + 1024]);
    xg2 = __builtin_nontemporal_load(&Xp[xrow + 2048]);
    xg3 = __builtin_nontemporal_load(&Xp[xrow + 3072]);
  }

  // ---- stage A (16x1024 h-block) -> LDS, inverse-swizzled source
  const char* hbase = (const char*)(hb + (size_t)b0 * 1024);
#pragma unroll
  for (int q = 0; q < 4; ++q) {
    int o = q * 8192 + tid * 16;    // linear LDS byte offset
    int row = o >> 11;              // 0..15
    int cb = o & 2047;
    const char* src = hbase + row * 2048 + (cb ^ ((row & 7) << 4));
    GLD16(src, smemA + q * 8192 + w * 1024);
  }

  // ---- bulk-preload B fragments (gate, 16 cols, this wave's K-half)
  const u16* Brow = Whh + (size_t)(gate * 1024 + hc0 + l15) * 1024
                        + kh * 512 + g4 * 8;
  short8 breg[16];
#pragma unroll
  for (int kk = 0; kk < 16; ++kk)
    breg[kk] = *(const short8*)(Brow + kk * 32);

  __syncthreads();   // drains GLD16 + breg loads

  // ---- 16 MFMAs, 4 chains, A from swizzled LDS
  f32x4 acc[4];
#pragma unroll
  for (int j = 0; j < 4; ++j) acc[j] = (f32x4)0.f;
#pragma unroll
  for (int kk = 0; kk < 16; ++kk) {
    int ctrue = (kh * 16 + kk) * 64 + g4 * 16;
    const short8 a = *(const short8*)(smemA + l15 * 2048 + (ctrue ^ ((l15 & 7) << 4)));
    acc[kk & 3] = __builtin_amdgcn_mfma_f32_16x16x32_bf16(a, breg[kk], acc[kk & 3], 0, 0, 0);
  }
  f32x4 asum = acc[0] + acc[1] + acc[2] + acc[3];
  {
    int m = g4 * 4;
#pragma unroll
    for (int e = 0; e < 4; ++e) lg[w][m + e][l15] = asum[e];
  }
  __syncthreads();

  // ---- cell update: 1 cell per thread (tid<256)
  if (tid < 256) {
    float gi = lg[0][bb][n] + lg[1][bb][n] + xg0;
    float gf = lg[2][bb][n] + lg[3][bb][n] + xg1;
    float gg = lg[4][bb][n] + lg[5][bb][n] + xg2;
    float go = lg[6][bb][n] + lg[7][bb][n] + xg3;
    float si = 1.f / (1.f + __expf(-gi));
    float sf = 1.f / (1.f + __expf(-gf));
    float so = 1.f / (1.f + __expf(-go));
    float tg = tanhf(gg);
    float cn = sf * cin + si * tg;
    float hn = so * tanhf(cn);
    c[ci] = cn;
    u16 h16 = f2bf(hn);
    hb_n[ci] = h16;
    if (hs_out) hs_out[((size_t)b * 64 + t) * 1024 + col] = h16;
    if (hT_out) hT_out[ci] = hn;
  }
}

// ---------------------------------------------------------------------------
// mean/logvar/latent + hd0 = [latent|cond_e] @ W_st^T + b_st -> bf16 h0; c=0.
__global__ __launch_bounds__(256) void latent_hd0_kernel(
    const float* hT, const float* Wm, const float* bm,
    const float* Wl, const float* bl, const float* Wst, const float* bst,
    const float* eps, const float* ce, u16* hb0, float* c) {
  __shared__ float red[64][4];
  __shared__ float ml[64];
  __shared__ float lat[40];
  int b = blockIdx.x;
  int tid = threadIdx.x;
  int o = tid >> 2, p = tid & 3;
  const float* w = (o < 32) ? (Wm + (size_t)o * 1024) : (Wl + (size_t)(o - 32) * 1024);
  const float* h = hT + (size_t)b * 1024;
  float s = 0.f;
  for (int k = p * 256; k < p * 256 + 256; ++k) s += h[k] * w[k];
  red[o][p] = s;
  __syncthreads();
  if (tid < 64) {
    float v = red[tid][0] + red[tid][1] + red[tid][2] + red[tid][3];
    v += (tid < 32) ? bm[tid] : bl[tid - 32];
    ml[tid] = v;
  }
  __syncthreads();
  if (tid < 32) lat[tid] = eps[b * 32 + tid] * __expf(0.5f * ml[32 + tid]) + ml[tid];
  if (tid >= 32 && tid < 40) lat[tid] = ce[b * 8 + (tid - 32)];
  __syncthreads();
  for (int hc = tid; hc < 1024; hc += 256) {
    float s2 = bst[hc];
    const float* wr = Wst + (size_t)hc * 40;
#pragma unroll
    for (int j = 0; j < 40; ++j) s2 += lat[j] * wr[j];
    int i = b * 1024 + hc;
    hb0[i] = f2bf(s2);
    c[i] = 0.f;
  }
}

// ---------------------------------------------------------------------------
extern "C" void kernel_launch(void* const* d_in, const int* in_sizes, int n_in,
                              void* d_out, int out_size, void* d_ws, size_t ws_size,
                              hipStream_t stream) {
  const int*   input_word = (const int*)d_in[0];
  const int*   cond       = (const int*)d_in[1];
  const float* emb_N      = (const float*)d_in[2];
  const float* Wih_N      = (const float*)d_in[3];
  const float* Whh_N      = (const float*)d_in[4];
  const float* bih_N      = (const float*)d_in[5];
  const float* bhh_N      = (const float*)d_in[6];
  const float* emb_D      = (const float*)d_in[7];
  const float* Wih_D      = (const float*)d_in[8];
  const float* Whh_D      = (const float*)d_in[9];
  const float* bih_D      = (const float*)d_in[10];
  const float* bhh_D      = (const float*)d_in[11];
  const float* emb_cond   = (const float*)d_in[12];
  const float* W_mean     = (const float*)d_in[13];
  const float* b_mean     = (const float*)d_in[14];
  const float* W_logvar   = (const float*)d_in[15];
  const float* b_logvar   = (const float*)d_in[16];
  const float* W_st       = (const float*)d_in[17];
  const float* b_st       = (const float*)d_in[18];
  const float* W_out      = (const float*)d_in[19];
  const float* b_out      = (const float*)d_in[20];
  const float* eps        = (const float*)d_in[21];
  float* out = (float*)d_out;

  char* ws = (char*)d_ws;
  size_t off = 0;
  auto alloc = [&](size_t b) { size_t p = off; off += (b + 255) & ~(size_t)255; return p; };
  u16*   wihN = (u16*)(ws + alloc(4096ull * 1024 * 2));
  u16*   whhN = (u16*)(ws + alloc(4096ull * 1024 * 2));
  u16*   wihD = (u16*)(ws + alloc(4096ull * 1024 * 2));
  u16*   whhD = (u16*)(ws + alloc(4096ull * 1024 * 2));
  u16*   wout = (u16*)(ws + alloc(32000ull * 1024 * 2));
  u16*   Xe   = (u16*)(ws + alloc(4096ull * 1024 * 2));
  u16*   Xd   = (u16*)(ws + alloc(4096ull * 1024 * 2));
  float* Xp   = (float*)(ws + alloc(4096ull * 4096 * 4));   // enc then dec
  u16*   hsd  = (u16*)(ws + alloc(4096ull * 1024 * 2));     // [b*64+t][1024]
  u16*   hb   = (u16*)(ws + alloc(2ull * 64 * 1024 * 2));   // bf16 h dbuf
  float* hf   = (float*)(ws + alloc(64ull * 1024 * 4));     // fp32 h_T (encoder)
  float* cbuf = (float*)(ws + alloc(64ull * 1024 * 4));     // fp32 cell state
  float* biasN = (float*)(ws + alloc(4096 * 4));
  float* biasD = (float*)(ws + alloc(4096 * 4));
  float* ce    = (float*)(ws + alloc(64 * 8 * 4));
  if (off > ws_size) return;

  conv_kernel<<<4096, 256, 0, stream>>>(Wih_N, wihN, 1048576);
  conv_kernel<<<4096, 256, 0, stream>>>(Whh_N, whhN, 1048576);
  conv_kernel<<<4096, 256, 0, stream>>>(Wih_D, wihD, 1048576);
  conv_kernel<<<4096, 256, 0, stream>>>(Whh_D, whhD, 1048576);
  conv_kernel<<<32000, 256, 0, stream>>>(W_out, wout, 8192000);
  prep_small<<<18, 256, 0, stream>>>(cond, emb_cond, bih_N, bhh_N, bih_D, bhh_D,
                                     ce, biasN, biasD);
  gather_kernel<<<4096, 256, 0, stream>>>(emb_N, input_word, Xe, 0);
  gather_kernel<<<4096, 256, 0, stream>>>(emb_D, input_word, Xd, 1);
  init_enc<<<256, 256, 0, stream>>>(ce, hb, cbuf);

  // encoder precompute + recurrence (256x128 tile: 16 m-tiles x 32 n-tiles)
  gemm_bt_kernel<false><<<512, 512, 0, stream>>>(Xe, wihN, Xp, biasN, 4096, 1024);
  for (int t = 0; t < 64; ++t) {
    u16* hcur = hb + (size_t)(t & 1) * 65536;
    u16* hnxt = hb + (size_t)((t + 1) & 1) * 65536;
    lstm_step3<<<256, 512, 0, stream>>>(hcur, whhN, Xp, cbuf, hnxt, nullptr,
                                        (t == 63) ? hf : nullptr, t);
  }
  // latent + decoder h0 (writes hb[0] and re-zeroes cell state)
  latent_hd0_kernel<<<64, 256, 0, stream>>>(hf, W_mean, b_mean, W_logvar, b_logvar,
                                            W_st, b_st, eps, ce, hb, cbuf);
  // decoder precompute + recurrence
  gemm_bt_kernel<false><<<512, 512, 0, stream>>>(Xd, wihD, Xp, biasD, 4096, 1024);
  for (int t = 0; t < 64; ++t) {
    u16* hcur = hb + (size_t)(t & 1) * 65536;
    u16* hnxt = hb + (size_t)((t + 1) & 1) * 65536;
    lstm_step3<<<256, 512, 0, stream>>>(hcur, whhD, Xp, cbuf, hnxt, hsd, nullptr, t);
  }
  // logits[b][t][:] = hsd[b*64+t] @ W_out^T + b_out
  // (16 m-tiles x 250 n-tiles = 4000 blocks, XCD swizzle, NT stores)
  gemm_bt_kernel<true><<<4000, 512, 0, stream>>>(hsd, wout, out, b_out, 32000, 1024);
}

// Round 11
// 1458.089 us; speedup vs baseline: 1.1399x; 1.0141x over previous
//
#include <hip/hip_runtime.h>
#include <hip/hip_bf16.h>

typedef unsigned short u16;
typedef unsigned int   u32;
typedef __attribute__((ext_vector_type(8))) short short8;   // 8 x bf16 (4 VGPRs)
typedef __attribute__((ext_vector_type(4))) float f32x4;

#define DEVINL static __device__ __forceinline__

// round-to-nearest-even f32 -> bf16
DEVINL u16 f2bf(float x) {
  u32 u = __float_as_uint(x);
  u32 r = (u + 0x7fffu + ((u >> 16) & 1u)) >> 16;
  return (u16)r;
}

// async global->LDS, 16B per lane. LDS dest = uniform base + lane*16.
#define GLD16(gp, lp) __builtin_amdgcn_global_load_lds(                     \
    (const __attribute__((address_space(1))) u32*)(gp),                     \
    (__attribute__((address_space(3))) u32*)(lp), 16, 0, 0)

// ---------------------------------------------------------------------------
// fp32 -> bf16 bulk convert, ALL five weight tensors in one launch.
// Segments: 4 x 1048576 chunks (Wih/Whh N,D) + 8192000 chunks (W_out).
__global__ __launch_bounds__(256) void conv_all(
    const float* __restrict__ s0, u16* __restrict__ d0,
    const float* __restrict__ s1, u16* __restrict__ d1,
    const float* __restrict__ s2, u16* __restrict__ d2,
    const float* __restrict__ s3, u16* __restrict__ d3,
    const float* __restrict__ s4, u16* __restrict__ d4) {
  const float* s; u16* d; int local;
  int blk = blockIdx.x;
  if (blk < 16384) {
    int p = blk >> 12; local = blk & 4095;
    s = (p == 0) ? s0 : (p == 1) ? s1 : (p == 2) ? s2 : s3;
    d = (p == 0) ? d0 : (p == 1) ? d1 : (p == 2) ? d2 : d3;
  } else {
    s = s4; d = d4; local = blk - 16384;
  }
  int i = local * 256 + threadIdx.x;
  float4 v = ((const float4*)s)[i];
  ushort4 o;
  o.x = f2bf(v.x); o.y = f2bf(v.y); o.z = f2bf(v.z); o.w = f2bf(v.w);
  ((ushort4*)d)[i] = o;
}

// cond_e gather + fused bias vectors (bih+bhh)
__global__ __launch_bounds__(256) void prep_small(
    const int* __restrict__ cond, const float* __restrict__ emb_cond,
    const float* __restrict__ bihN, const float* __restrict__ bhhN,
    const float* __restrict__ bihD, const float* __restrict__ bhhD,
    float* __restrict__ ce, float* __restrict__ biasN, float* __restrict__ biasD) {
  int tid = blockIdx.x * 256 + threadIdx.x;
  if (tid < 512) {
    int b = tid >> 3, j = tid & 7;
    ce[tid] = emb_cond[cond[b] * 8 + j];
  }
  int i = tid - 512;
  if (i >= 0 && i < 4096) {
    biasN[i] = bihN[i] + bhhN[i];
    biasD[i] = bihD[i] + bhhD[i];
  }
}

// encoder h0 = [zeros(B,1016), cond_e] -> bf16 into hbuf[0]; c0 = 0
__global__ __launch_bounds__(256) void init_enc(const float* __restrict__ ce,
                                                u16* __restrict__ hb0,
                                                float* __restrict__ c) {
  int tid = blockIdx.x * 256 + threadIdx.x;   // 64*1024
  int b = tid >> 10, col = tid & 1023;
  float v = (col >= 1016) ? ce[b * 8 + (col - 1016)] : 0.f;
  hb0[tid] = f2bf(v);
  c[tid] = 0.f;
}

// embedding row gather -> bf16, X[t*64+b][1024]
__global__ __launch_bounds__(256) void gather_kernel(const float* __restrict__ emb,
                                                     const int* __restrict__ words,
                                                     u16* __restrict__ X, int dec) {
  int r = blockIdx.x;                    // r = t*64 + b
  int t = r >> 6, b = r & 63;
  int tok = dec ? ((t == 0) ? 0 : words[b * 64 + t - 1]) : words[b * 64 + t];
  float4 v = ((const float4*)(emb + (size_t)tok * 1024))[threadIdx.x];
  ushort4 o;
  o.x = f2bf(v.x); o.y = f2bf(v.y); o.z = f2bf(v.z); o.w = f2bf(v.w);
  ((ushort4*)(X + (size_t)r * 1024))[threadIdx.x] = o;
}

// ---------------------------------------------------------------------------
// C = A(MxK) * B(NxK)^T + bias, bf16 in, fp32 out. 256x128 tile, BK=32,
// 512 threads = 8 waves (4m x 2n), per-wave 64x64 output.
// MODE 0 (square Xp GEMMs, 512 blocks): n-fast + bijective XCD swizzle.
// MODE 1 (logits M=4096 N=32000, 4096 blocks): per-XCD n-partition —
//   XCD x (= blockIdx%8, round-robin dispatch) owns n-tiles n%8==x, walked
//   mg(8) x kn(32) x mi(2): A window 1MB L2-hot, each B panel HBM-fetched
//   ~once globally (L3-served to other XCDs). 96 dummy blocks (250%8!=0).
//   NT stores on C (512MB stream must not evict W_out).
template <int MODE>
__global__ __launch_bounds__(512) void gemm_bt_kernel(
    const u16* __restrict__ A, const u16* __restrict__ B,
    float* __restrict__ C, const float* __restrict__ bias, int N, int K) {
  __shared__ u16 lA[256 * 32];   // 16KB
  __shared__ u16 lB[128 * 32];   // 8KB
  const int tid = threadIdx.x;
  const int lane = tid & 63;
  const int wid = tid >> 6;      // 0..7

  int tile_m, tile_n;
  if (MODE == 0) {
    const int nn = N >> 7;                          // # n-tiles
    const int nwg = gridDim.x;
    const int orig = blockIdx.x;
    const int wgid = (orig & 7) * (nwg >> 3) + (orig >> 3);
    tile_m = (wgid / nn) * 256;
    tile_n = (wgid % nn) * 128;
  } else {
    const int i = blockIdx.x;        // 0..4095
    const int x = i & 7;             // XCD id (round-robin dispatch)
    const int k = i >> 3;            // 0..511 within XCD
    const int mg = k >> 6;           // m-group of 2 (0..7)
    const int r  = k & 63;
    const int kn = r >> 1;           // n-slot (0..31)
    const int mi = r & 1;
    const int tn = kn * 8 + x;
    if (tn >= 250) return;           // dummy
    tile_m = (mg * 2 + mi) * 256;
    tile_n = tn * 128;
  }
  const int wm = wid >> 1, wn = wid & 1;          // 4 x 2 waves

  const int ldr = lane >> 2;
  const int lko = (lane & 3) * 8;
  const int l15 = lane & 15;
  const int g4 = lane >> 4;

  f32x4 acc[4][4];
#pragma unroll
  for (int i = 0; i < 4; ++i)
#pragma unroll
    for (int j = 0; j < 4; ++j) acc[i][j] = (f32x4)0.f;

  const size_t aBase = (size_t)tile_m * K;
  const size_t bBase = (size_t)tile_n * K;

  for (int k0 = 0; k0 < K; k0 += 32) {
    __syncthreads();
    // A: 16 chunks of 16 rows (2 per wave); B: 8 chunks (1 per wave)
#pragma unroll
    for (int q = 0; q < 2; ++q) {
      int ch = wid * 2 + q;
      int row = ch * 16 + ldr;
      GLD16(A + aBase + (size_t)row * K + k0 + lko, &lA[ch * 512]);
    }
    {
      int row = wid * 16 + ldr;
      GLD16(B + bBase + (size_t)row * K + k0 + lko, &lB[wid * 512]);
    }
    __syncthreads();
    short8 af[4], bf[4];
#pragma unroll
    for (int i = 0; i < 4; ++i)
      af[i] = *(const short8*)&lA[(wm * 64 + i * 16 + l15) * 32 + g4 * 8];
#pragma unroll
    for (int j = 0; j < 4; ++j)
      bf[j] = *(const short8*)&lB[(wn * 64 + j * 16 + l15) * 32 + g4 * 8];
#pragma unroll
    for (int i = 0; i < 4; ++i)
#pragma unroll
      for (int j = 0; j < 4; ++j)
        acc[i][j] = __builtin_amdgcn_mfma_f32_16x16x32_bf16(af[i], bf[j], acc[i][j], 0, 0, 0);
  }

#pragma unroll
  for (int i = 0; i < 4; ++i) {
    int row0 = tile_m + wm * 64 + i * 16 + (g4 << 2);
#pragma unroll
    for (int j = 0; j < 4; ++j) {
      int col = tile_n + wn * 64 + j * 16 + l15;
      float bv = bias[col];
#pragma unroll
      for (int e = 0; e < 4; ++e) {
        size_t o = (size_t)(row0 + e) * (size_t)N + col;
        float v = acc[i][j][e] + bv;
        if (MODE == 1) __builtin_nontemporal_store(v, &C[o]);
        else           C[o] = v;
      }
    }
  }
}

// ---------------------------------------------------------------------------
// One LSTM step, 256 WGs x 512 threads (8 waves). WG (cg,bg): h-cols
// [cg*16,+16), batches [bg*16,+16); XCD-affine decode. Wave w: gate = w>>1,
// K-half = w&1 (16 MFMAs from 16 breg short8). A staged once into XOR-
// swizzled LDS via GLD16 (pre-swizzled source, linear dest). Partials
// summed via 8-slot LDS exchange. hsd written [b*64+t] order.
__global__ __launch_bounds__(512) void lstm_step3(
    const u16* __restrict__ hb,    // h_t bf16 [64][1024]
    const u16* __restrict__ Whh,   // bf16 [4096][1024]
    const float* __restrict__ Xp,  // fp32 [4096][4096]
    float* __restrict__ c,         // fp32 [64][1024], in-place
    u16* __restrict__ hb_n,        // h_{t+1} bf16
    u16* __restrict__ hs_out,      // decoder: hsd base ([b*64+t]), else null
    float* __restrict__ hT_out,    // encoder t==63: fp32 h_T, else null
    int t) {
  __shared__ __align__(16) char smemA[32768];   // 16 rows x 2048B, swizzled
  __shared__ float lg[8][16][16];               // [wave][batch][col]
  const int tid = threadIdx.x;      // 0..511
  const int lane = tid & 63;
  const int w = tid >> 6;           // wave 0..7
  const int gate = w >> 1;
  const int kh = w & 1;             // K-half
  const int i = blockIdx.x;
  const int cg = ((i >> 5) << 3) | (i & 7);   // col-group (cg%8 = XCD)
  const int bg = (i >> 3) & 3;
  const int hc0 = cg * 16;
  const int b0 = bg * 16;
  const int l15 = lane & 15;
  const int g4 = lane >> 4;

  // ---- epilogue operand prefetch (update threads only)
  const int bb = tid >> 4, n = tid & 15;      // valid for tid<256
  const int b = b0 + bb, col = hc0 + n;
  const int ci = b * 1024 + col;
  float cin = 0.f, xg0 = 0.f, xg1 = 0.f, xg2 = 0.f, xg3 = 0.f;
  if (tid < 256) {
    cin = c[ci];
    size_t xrow = (size_t)(t * 64 + b) * 4096 + col;
    xg0 = __builtin_nontemporal_load(&Xp[xrow]);
    xg1 = __builtin_nontemporal_load(&Xp[xrow + 1024]);
    xg2 = __builtin_nontemporal_load(&Xp[xrow + 2048]);
    xg3 = __builtin_nontemporal_load(&Xp[xrow + 3072]);
  }

  // ---- stage A (16x1024 h-block) -> LDS, inverse-swizzled source
  const char* hbase = (const char*)(hb + (size_t)b0 * 1024);
#pragma unroll
  for (int q = 0; q < 4; ++q) {
    int o = q * 8192 + tid * 16;    // linear LDS byte offset
    int row = o >> 11;              // 0..15
    int cb = o & 2047;
    const char* src = hbase + row * 2048 + (cb ^ ((row & 7) << 4));
    GLD16(src, smemA + q * 8192 + w * 1024);
  }

  // ---- bulk-preload B fragments (gate, 16 cols, this wave's K-half)
  const u16* Brow = Whh + (size_t)(gate * 1024 + hc0 + l15) * 1024
                        + kh * 512 + g4 * 8;
  short8 breg[16];
#pragma unroll
  for (int kk = 0; kk < 16; ++kk)
    breg[kk] = *(const short8*)(Brow + kk * 32);

  __syncthreads();   // drains GLD16 + breg loads

  // ---- 16 MFMAs, 4 chains, A from swizzled LDS
  f32x4 acc[4];
#pragma unroll
  for (int j = 0; j < 4; ++j) acc[j] = (f32x4)0.f;
#pragma unroll
  for (int kk = 0; kk < 16; ++kk) {
    int ctrue = (kh * 16 + kk) * 64 + g4 * 16;
    const short8 a = *(const short8*)(smemA + l15 * 2048 + (ctrue ^ ((l15 & 7) << 4)));
    acc[kk & 3] = __builtin_amdgcn_mfma_f32_16x16x32_bf16(a, breg[kk], acc[kk & 3], 0, 0, 0);
  }
  f32x4 asum = acc[0] + acc[1] + acc[2] + acc[3];
  {
    int m = g4 * 4;
#pragma unroll
    for (int e = 0; e < 4; ++e) lg[w][m + e][l15] = asum[e];
  }
  __syncthreads();

  // ---- cell update: 1 cell per thread (tid<256)
  if (tid < 256) {
    float gi = lg[0][bb][n] + lg[1][bb][n] + xg0;
    float gf = lg[2][bb][n] + lg[3][bb][n] + xg1;
    float gg = lg[4][bb][n] + lg[5][bb][n] + xg2;
    float go = lg[6][bb][n] + lg[7][bb][n] + xg3;
    float si = 1.f / (1.f + __expf(-gi));
    float sf = 1.f / (1.f + __expf(-gf));
    float so = 1.f / (1.f + __expf(-go));
    float tg = tanhf(gg);
    float cn = sf * cin + si * tg;
    float hn = so * tanhf(cn);
    c[ci] = cn;
    u16 h16 = f2bf(hn);
    hb_n[ci] = h16;
    if (hs_out) hs_out[((size_t)b * 64 + t) * 1024 + col] = h16;
    if (hT_out) hT_out[ci] = hn;
  }
}

// ---------------------------------------------------------------------------
// mean/logvar/latent + hd0 = [latent|cond_e] @ W_st^T + b_st -> bf16 h0; c=0.
__global__ __launch_bounds__(256) void latent_hd0_kernel(
    const float* hT, const float* Wm, const float* bm,
    const float* Wl, const float* bl, const float* Wst, const float* bst,
    const float* eps, const float* ce, u16* hb0, float* c) {
  __shared__ float red[64][4];
  __shared__ float ml[64];
  __shared__ float lat[40];
  int b = blockIdx.x;
  int tid = threadIdx.x;
  int o = tid >> 2, p = tid & 3;
  const float* w = (o < 32) ? (Wm + (size_t)o * 1024) : (Wl + (size_t)(o - 32) * 1024);
  const float* h = hT + (size_t)b * 1024;
  float s = 0.f;
  for (int k = p * 256; k < p * 256 + 256; ++k) s += h[k] * w[k];
  red[o][p] = s;
  __syncthreads();
  if (tid < 64) {
    float v = red[tid][0] + red[tid][1] + red[tid][2] + red[tid][3];
    v += (tid < 32) ? bm[tid] : bl[tid - 32];
    ml[tid] = v;
  }
  __syncthreads();
  if (tid < 32) lat[tid] = eps[b * 32 + tid] * __expf(0.5f * ml[32 + tid]) + ml[tid];
  if (tid >= 32 && tid < 40) lat[tid] = ce[b * 8 + (tid - 32)];
  __syncthreads();
  for (int hc = tid; hc < 1024; hc += 256) {
    float s2 = bst[hc];
    const float* wr = Wst + (size_t)hc * 40;
#pragma unroll
    for (int j = 0; j < 40; ++j) s2 += lat[j] * wr[j];
    int i = b * 1024 + hc;
    hb0[i] = f2bf(s2);
    c[i] = 0.f;
  }
}

// ---------------------------------------------------------------------------
extern "C" void kernel_launch(void* const* d_in, const int* in_sizes, int n_in,
                              void* d_out, int out_size, void* d_ws, size_t ws_size,
                              hipStream_t stream) {
  const int*   input_word = (const int*)d_in[0];
  const int*   cond       = (const int*)d_in[1];
  const float* emb_N      = (const float*)d_in[2];
  const float* Wih_N      = (const float*)d_in[3];
  const float* Whh_N      = (const float*)d_in[4];
  const float* bih_N      = (const float*)d_in[5];
  const float* bhh_N      = (const float*)d_in[6];
  const float* emb_D      = (const float*)d_in[7];
  const float* Wih_D      = (const float*)d_in[8];
  const float* Whh_D      = (const float*)d_in[9];
  const float* bih_D      = (const float*)d_in[10];
  const float* bhh_D      = (const float*)d_in[11];
  const float* emb_cond   = (const float*)d_in[12];
  const float* W_mean     = (const float*)d_in[13];
  const float* b_mean     = (const float*)d_in[14];
  const float* W_logvar   = (const float*)d_in[15];
  const float* b_logvar   = (const float*)d_in[16];
  const float* W_st       = (const float*)d_in[17];
  const float* b_st       = (const float*)d_in[18];
  const float* W_out      = (const float*)d_in[19];
  const float* b_out      = (const float*)d_in[20];
  const float* eps        = (const float*)d_in[21];
  float* out = (float*)d_out;

  char* ws = (char*)d_ws;
  size_t off = 0;
  auto alloc = [&](size_t b) { size_t p = off; off += (b + 255) & ~(size_t)255; return p; };
  u16*   wihN = (u16*)(ws + alloc(4096ull * 1024 * 2));
  u16*   whhN = (u16*)(ws + alloc(4096ull * 1024 * 2));
  u16*   wihD = (u16*)(ws + alloc(4096ull * 1024 * 2));
  u16*   whhD = (u16*)(ws + alloc(4096ull * 1024 * 2));
  u16*   wout = (u16*)(ws + alloc(32000ull * 1024 * 2));
  u16*   Xe   = (u16*)(ws + alloc(4096ull * 1024 * 2));
  u16*   Xd   = (u16*)(ws + alloc(4096ull * 1024 * 2));
  float* Xp   = (float*)(ws + alloc(4096ull * 4096 * 4));   // enc then dec
  u16*   hsd  = (u16*)(ws + alloc(4096ull * 1024 * 2));     // [b*64+t][1024]
  u16*   hb   = (u16*)(ws + alloc(2ull * 64 * 1024 * 2));   // bf16 h dbuf
  float* hf   = (float*)(ws + alloc(64ull * 1024 * 4));     // fp32 h_T (encoder)
  float* cbuf = (float*)(ws + alloc(64ull * 1024 * 4));     // fp32 cell state
  float* biasN = (float*)(ws + alloc(4096 * 4));
  float* biasD = (float*)(ws + alloc(4096 * 4));
  float* ce    = (float*)(ws + alloc(64 * 8 * 4));
  if (off > ws_size) return;

  conv_all<<<48384, 256, 0, stream>>>(Wih_N, wihN, Whh_N, whhN,
                                      Wih_D, wihD, Whh_D, whhD, W_out, wout);
  prep_small<<<18, 256, 0, stream>>>(cond, emb_cond, bih_N, bhh_N, bih_D, bhh_D,
                                     ce, biasN, biasD);
  gather_kernel<<<4096, 256, 0, stream>>>(emb_N, input_word, Xe, 0);
  gather_kernel<<<4096, 256, 0, stream>>>(emb_D, input_word, Xd, 1);
  init_enc<<<256, 256, 0, stream>>>(ce, hb, cbuf);

  // encoder precompute + recurrence (256x128 tile: 16 m-tiles x 32 n-tiles)
  gemm_bt_kernel<0><<<512, 512, 0, stream>>>(Xe, wihN, Xp, biasN, 4096, 1024);
  for (int t = 0; t < 64; ++t) {
    u16* hcur = hb + (size_t)(t & 1) * 65536;
    u16* hnxt = hb + (size_t)((t + 1) & 1) * 65536;
    lstm_step3<<<256, 512, 0, stream>>>(hcur, whhN, Xp, cbuf, hnxt, nullptr,
                                        (t == 63) ? hf : nullptr, t);
  }
  // latent + decoder h0 (writes hb[0] and re-zeroes cell state)
  latent_hd0_kernel<<<64, 256, 0, stream>>>(hf, W_mean, b_mean, W_logvar, b_logvar,
                                            W_st, b_st, eps, ce, hb, cbuf);
  // decoder precompute + recurrence
  gemm_bt_kernel<0><<<512, 512, 0, stream>>>(Xd, wihD, Xp, biasD, 4096, 1024);
  for (int t = 0; t < 64; ++t) {
    u16* hcur = hb + (size_t)(t & 1) * 65536;
    u16* hnxt = hb + (size_t)((t + 1) & 1) * 65536;
    lstm_step3<<<256, 512, 0, stream>>>(hcur, whhD, Xp, cbuf, hnxt, hsd, nullptr, t);
  }
  // logits[b][t][:] = hsd[b*64+t] @ W_out^T + b_out
  // (per-XCD n-partition, 4096 blocks, NT stores)
  gemm_bt_kernel<1><<<4096, 512, 0, stream>>>(hsd, wout, out, b_out, 32000, 1024);
}